// Round 7
// baseline (991.931 us; speedup 1.0000x reference)
//
#include <hip/hip_runtime.h>
#include <hip/hip_bf16.h>
#include <stdint.h>
#include <stddef.h>

// ---------------------------------------------------------------------------
// Swin-V2 window attention, MI355X.  fp16-hi/lo ("fp16x2") everywhere.
// R6: k_qkv rewritten — B (=x) fragments loaded straight from global into
// registers (wave-private, no LDS round-trip, no write conflicts), cvt to
// fp16 hi/lo in-reg; wave tile widened to 64x128 (j=0..7) for 2x A reuse.
// A (=W hi/lo) stays global_load_lds double-buffered; barrier guards A only.
// k_proj / k_attn unchanged from R5 (known-good).
// (R7 = R6 resubmitted verbatim: R6 bench never ran — GPU acquisition timeout.)
// ---------------------------------------------------------------------------

typedef unsigned short ushort_t;
typedef _Float16 half_t;
typedef __attribute__((ext_vector_type(8))) _Float16 half8;   // 4 VGPR
typedef __attribute__((ext_vector_type(4))) float f32x4;

#define MROWS 65536   // 1024 windows * 64 tokens

__device__ __forceinline__ ushort_t h_bits(half_t h) {
  union { half_t h; ushort_t u; } c; c.h = h; return c.u;
}

__device__ __forceinline__ void gload16(const void* g, void* l) {
  __builtin_amdgcn_global_load_lds(
      (const __attribute__((address_space(1))) unsigned int*)g,
      (__attribute__((address_space(3))) unsigned int*)l, 16, 0, 0);
}

// ---------------- split fp32 -> fp16 hi + fp16 lo (weights only) -----------
__global__ __launch_bounds__(256) void k_split(const float* __restrict__ src,
                                               ushort_t* __restrict__ hi,
                                               ushort_t* __restrict__ lo, int n4) {
  int stride = gridDim.x * blockDim.x;
  for (int i = blockIdx.x * blockDim.x + threadIdx.x; i < n4; i += stride) {
    f32x4 x = reinterpret_cast<const f32x4*>(src)[i];
    ushort_t h4[4], l4[4];
#pragma unroll
    for (int j = 0; j < 4; ++j) {
      half_t hh = (half_t)x[j];
      h4[j] = h_bits(hh);
      l4[j] = h_bits((half_t)(x[j] - (float)hh));
    }
    reinterpret_cast<uint2*>(hi)[i] =
        make_uint2(h4[0] | ((unsigned)h4[1] << 16), h4[2] | ((unsigned)h4[3] << 16));
    reinterpret_cast<uint2*>(lo)[i] =
        make_uint2(l4[0] | ((unsigned)l4[1] << 16), l4[2] | ((unsigned)l4[3] << 16));
  }
}

// ---------------- CPB MLP: 225 positions -> 16*sigmoid table ---------------
__global__ __launch_bounds__(256) void k_cpb1(const float* __restrict__ coords,
                                              const float* __restrict__ w1,
                                              const float* __restrict__ b1,
                                              const float* __restrict__ w2,
                                              float* __restrict__ tbl) {
  __shared__ float hid[512];
  int p = blockIdx.x;
  float c0 = coords[2 * p], c1 = coords[2 * p + 1];
  int t = threadIdx.x;
  for (int j = t; j < 512; j += 256) {
    float v = c0 * w1[2 * j] + c1 * w1[2 * j + 1] + b1[j];
    hid[j] = v > 0.f ? v : 0.f;
  }
  __syncthreads();
  int wid = t >> 6, lane = t & 63;
#pragma unroll
  for (int hh = 0; hh < 4; ++hh) {
    int head = wid * 4 + hh;
    float s = 0.f;
    for (int j = lane; j < 512; j += 64) s += hid[j] * w2[head * 512 + j];
#pragma unroll
    for (int off = 32; off > 0; off >>= 1) s += __shfl_xor(s, off);
    if (lane == 0) tbl[p * 16 + head] = 16.f / (1.f + __expf(-s));
  }
}

__global__ __launch_bounds__(256) void k_cpb2(const float* __restrict__ tbl,
                                              const int* __restrict__ ridx,
                                              float* __restrict__ rpb) {
  int idx = blockIdx.x * 256 + threadIdx.x;   // 65536 = 16 heads * 4096
  int h = idx >> 12, nm = idx & 4095;
  rpb[idx] = tbl[ridx[nm] * 16 + h];
}

// ---------------- QKV GEMM: C[ch,tok] = W[ch,K] * X[tok,K]^T ---------------
// Tile 128ch x 256tok, 4 waves (2x2), wave tile 64x128.
// A = W hi/lo via global_load_lds (dbuf, XOR swizzle); B = x fp32 loaded
// per-wave straight from global (lane reads 32B of its column), cvt in reg.
__global__ __launch_bounds__(256, 2) void k_qkv(
    const ushort_t* __restrict__ Wh, const ushort_t* __restrict__ Wl,
    const float* __restrict__ X,
    const float* __restrict__ qb, const float* __restrict__ vb,
    ushort_t* __restrict__ oqh, ushort_t* __restrict__ oql,
    ushort_t* __restrict__ okh, ushort_t* __restrict__ okl,
    ushort_t* __restrict__ ovt) {
  __shared__ ushort_t lAh[2][4096];
  __shared__ ushort_t lAl[2][4096];

  int nwg = gridDim.x, bid = blockIdx.x;
  int idx = ((nwg & 7) == 0) ? ((bid & 7) * (nwg >> 3) + (bid >> 3)) : bid;
  int tm = idx % 12, tn = idx / 12;   // consecutive idx share tn (x L2/L1 reuse)
  int tid = threadIdx.x;
  int wid = tid >> 6, lane = tid & 63;
  int wr = wid >> 1, wc = wid & 1;
  int lr = lane & 15, lq = lane >> 4;

  // A staging: 2 sweeps/plane, linear LDS dest + source-side XOR swizzle
  int rA = tid >> 2, qA = tid & 3;
  size_t gA = (size_t)(tm * 128 + rA) * 512 + ((qA ^ (rA & 3)) << 3);
  int dA = wid * 512;

  // B: lane owns column (wc*128 + j*16 + lr), k-slot lq*8..+7 (32B)
  const float* xb = X + (size_t)(tn * 256 + wc * 128 + lr) * 512 + lq * 8;

  f32x4 acc[4][8];
#pragma unroll
  for (int i = 0; i < 4; ++i)
#pragma unroll
    for (int j = 0; j < 8; ++j)
#pragma unroll
      for (int r = 0; r < 4; ++r) acc[i][j][r] = 0.f;

  auto stageA = [&](int kk, int bs) {
    gload16(Wh + gA + kk, &lAh[bs][dA]);
    gload16(Wh + gA + 32768 + kk, &lAh[bs][2048 + dA]);
    gload16(Wl + gA + kk, &lAl[bs][dA]);
    gload16(Wl + gA + 32768 + kk, &lAl[bs][2048 + dA]);
  };

  stageA(0, 0);
  const int c16 = (lq ^ (lr & 3)) << 3;   // read-side inverse swizzle
#pragma unroll 2
  for (int t = 0; t < 16; ++t) {
    __syncthreads();
    int bs = t & 1, kk = t * 32;
    if (t < 15) stageA(kk + 32, bs ^ 1);

    // issue first two j-frags (depth-2 ping-pong)
    f32x4 x0a = *(const f32x4*)(xb + kk);
    f32x4 x0b = *(const f32x4*)(xb + kk + 4);
    f32x4 x1a = *(const f32x4*)(xb + 8192 + kk);
    f32x4 x1b = *(const f32x4*)(xb + 8192 + kk + 4);

    half8 ah[4], al[4];
#pragma unroll
    for (int i = 0; i < 4; ++i) {
      int ro = (wr * 64 + i * 16 + lr) * 32 + c16;
      ah[i] = *(const half8*)&lAh[bs][ro];
      al[i] = *(const half8*)&lAl[bs][ro];
    }

#pragma unroll
    for (int j = 0; j < 8; ++j) {
      f32x4 ca = (j & 1) ? x1a : x0a;
      f32x4 cb = (j & 1) ? x1b : x0b;
      if (j < 6) {                         // prefetch j+2 into the slot just freed
        const float* p = xb + (size_t)(j + 2) * 8192 + kk;
        if (j & 1) { x1a = *(const f32x4*)p; x1b = *(const f32x4*)(p + 4); }
        else       { x0a = *(const f32x4*)p; x0b = *(const f32x4*)(p + 4); }
      }
      half8 bh, bl;
#pragma unroll
      for (int e = 0; e < 4; ++e) {
        half_t h0 = (half_t)ca[e];
        bh[e] = h0;
        bl[e] = (half_t)(ca[e] - (float)h0);
        half_t h1 = (half_t)cb[e];
        bh[4 + e] = h1;
        bl[4 + e] = (half_t)(cb[e] - (float)h1);
      }
#pragma unroll
      for (int i = 0; i < 4; ++i) {
        acc[i][j] = __builtin_amdgcn_mfma_f32_16x16x32_f16(ah[i], bh, acc[i][j], 0, 0, 0);
        acc[i][j] = __builtin_amdgcn_mfma_f32_16x16x32_f16(ah[i], bl, acc[i][j], 0, 0, 0);
        acc[i][j] = __builtin_amdgcn_mfma_f32_16x16x32_f16(al[i], bh, acc[i][j], 0, 0, 0);
      }
    }
  }

  // C layout: col = lane&15 (token), row = (lane>>4)*4 + reg (channel)
#pragma unroll
  for (int i = 0; i < 4; ++i) {
    int ch0 = tm * 128 + wr * 64 + i * 16 + lq * 4;
#pragma unroll
    for (int j = 0; j < 8; ++j) {
      int tok = tn * 256 + wc * 128 + j * 16 + lr;
      int sec = tm >> 2;                 // block-uniform: 0=q,1=k,2=v
      int h = (ch0 >> 5) & 15, d0 = ch0 & 31;
      int win = tok >> 6, n = tok & 63;
      size_t pr = (size_t)win * 16 + h;
      f32x4 b4;
      if (sec == 0)      b4 = *(const f32x4*)&qb[ch0];
      else if (sec == 2) b4 = *(const f32x4*)&vb[ch0 - 1024];
      else { b4[0] = 0.f; b4[1] = 0.f; b4[2] = 0.f; b4[3] = 0.f; }
      if (sec == 2) {
#pragma unroll
        for (int r = 0; r < 4; ++r) {
          float v = acc[i][j][r] + b4[r];
          ovt[(pr * 32 + d0 + r) * 64 + n] = h_bits((half_t)v);
        }
      } else {
        ushort_t hb[4], lb4[4];
#pragma unroll
        for (int r = 0; r < 4; ++r) {
          float v = acc[i][j][r] + b4[r];
          half_t hh = (half_t)v;
          hb[r] = h_bits(hh);
          lb4[r] = h_bits((half_t)(v - (float)hh));
        }
        uint2 hw = make_uint2(hb[0] | ((unsigned)hb[1] << 16), hb[2] | ((unsigned)hb[3] << 16));
        uint2 lw = make_uint2(lb4[0] | ((unsigned)lb4[1] << 16), lb4[2] | ((unsigned)lb4[3] << 16));
        size_t o = (pr * 64 + n) * 32 + d0;
        if (sec == 0) { *(uint2*)&oqh[o] = hw; *(uint2*)&oql[o] = lw; }
        else          { *(uint2*)&okh[o] = hw; *(uint2*)&okl[o] = lw; }
      }
    }
  }
}

// ---------------- proj GEMM: C[ch,tok] = W[ch,K] * AO[tok,K]^T -------------
// A = Wp hi/lo co-resident; B = attn-out fp16 (hi only). 32 MFMA / barrier.
__global__ __launch_bounds__(256, 2) void k_proj(
    const ushort_t* __restrict__ Wh, const ushort_t* __restrict__ Wl,
    const ushort_t* __restrict__ Bp,
    const float* __restrict__ pb, float* __restrict__ outp) {
  __shared__ ushort_t lAh[2][4096];
  __shared__ ushort_t lAl[2][4096];
  __shared__ ushort_t lBh[2][4096];

  int nwg = gridDim.x, bid = blockIdx.x;
  int idx = ((nwg & 7) == 0) ? ((bid & 7) * (nwg >> 3) + (bid >> 3)) : bid;
  int tm = idx % 4, tn = idx / 4;
  int tid = threadIdx.x;
  int wid = tid >> 6, lane = tid & 63;
  int wr = wid >> 1, wc = wid & 1;
  int lr = lane & 15, lq = lane >> 4;

  int rA = tid >> 2, qA = tid & 3;
  int sw = (qA ^ (rA & 3)) << 3;
  size_t gA = (size_t)(tm * 128 + rA) * 512 + sw;
  size_t gB = (size_t)(tn * 128 + rA) * 512 + sw;
  int dA = wid * 512;

  f32x4 acc[4][4];
#pragma unroll
  for (int i = 0; i < 4; ++i)
#pragma unroll
    for (int j = 0; j < 4; ++j)
#pragma unroll
      for (int r = 0; r < 4; ++r) acc[i][j][r] = 0.f;

  auto stage = [&](int kk, int bs) {
    gload16(Wh + gA + kk, &lAh[bs][dA]);
    gload16(Wh + gA + 32768 + kk, &lAh[bs][2048 + dA]);
    gload16(Wl + gA + kk, &lAl[bs][dA]);
    gload16(Wl + gA + 32768 + kk, &lAl[bs][2048 + dA]);
    gload16(Bp + gB + kk, &lBh[bs][dA]);
    gload16(Bp + gB + 32768 + kk, &lBh[bs][2048 + dA]);
  };

  stage(0, 0);
  const int c16 = (lq ^ (lr & 3)) << 3;
#pragma unroll 2
  for (int t = 0; t < 16; ++t) {
    __syncthreads();
    int bs = t & 1;
    if (t < 15) stage((t + 1) * 32, bs ^ 1);
    half8 ah[4], al[4], bh[4];
#pragma unroll
    for (int i = 0; i < 4; ++i) {
      int ro = (wr * 64 + i * 16 + lr) * 32 + c16;
      ah[i] = *(const half8*)&lAh[bs][ro];
      al[i] = *(const half8*)&lAl[bs][ro];
    }
#pragma unroll
    for (int j = 0; j < 4; ++j)
      bh[j] = *(const half8*)&lBh[bs][(wc * 64 + j * 16 + lr) * 32 + c16];
#pragma unroll
    for (int i = 0; i < 4; ++i)
#pragma unroll
      for (int j = 0; j < 4; ++j) {
        acc[i][j] = __builtin_amdgcn_mfma_f32_16x16x32_f16(ah[i], bh[j], acc[i][j], 0, 0, 0);
        acc[i][j] = __builtin_amdgcn_mfma_f32_16x16x32_f16(al[i], bh[j], acc[i][j], 0, 0, 0);
      }
  }

#pragma unroll
  for (int i = 0; i < 4; ++i) {
    int ch0 = tm * 128 + wr * 64 + i * 16 + lq * 4;
    f32x4 b4 = *(const f32x4*)&pb[ch0];
#pragma unroll
    for (int j = 0; j < 4; ++j) {
      int tok = tn * 128 + wc * 64 + j * 16 + lr;
      f32x4 o;
#pragma unroll
      for (int r = 0; r < 4; ++r) o[r] = acc[i][j][r] + b4[r];
      *(f32x4*)&outp[(size_t)tok * 512 + ch0] = o;
    }
  }
}

// ---------------- MFMA attention: 1 wave per (window,head) -----------------
__global__ __launch_bounds__(128) void k_attn(
    const ushort_t* __restrict__ qph, const ushort_t* __restrict__ qpl,
    const ushort_t* __restrict__ kph, const ushort_t* __restrict__ kpl,
    const ushort_t* __restrict__ vt,
    const float* __restrict__ rpb, const float* __restrict__ lsc,
    ushort_t* __restrict__ oh) {
  __shared__ unsigned pw[2][2][64 * 36];   // [wave][P hi/lo][q row * 36 words]
  const int tid = threadIdx.x;
  const int wid = tid >> 6, lane = tid & 63;
  const int pair = blockIdx.x * 2 + wid;   // window*16 + head
  const int h = pair & 15;
  const int l15 = lane & 15, lq = lane >> 4;
  const size_t base = (size_t)pair * 2048;

  half8 Kh[4], Kl[4], Qh[4], Ql[4];
#pragma unroll
  for (int t4 = 0; t4 < 4; ++t4) {
    int off = (t4 * 16 + l15) * 32 + lq * 8;
    Kh[t4] = *(const half8*)(kph + base + off);
    Kl[t4] = *(const half8*)(kpl + base + off);
    Qh[t4] = *(const half8*)(qph + base + off);
    Ql[t4] = *(const half8*)(qpl + base + off);
  }
  f32x4 st[4][4];                          // [kvt][qt]
#pragma unroll
  for (int a = 0; a < 4; ++a)
#pragma unroll
    for (int b = 0; b < 4; ++b)
#pragma unroll
      for (int r = 0; r < 4; ++r) st[a][b][r] = 0.f;
#pragma unroll
  for (int kvt = 0; kvt < 4; ++kvt)
#pragma unroll
    for (int qt = 0; qt < 4; ++qt) {
      st[kvt][qt] = __builtin_amdgcn_mfma_f32_16x16x32_f16(Kh[kvt], Qh[qt], st[kvt][qt], 0, 0, 0);
      st[kvt][qt] = __builtin_amdgcn_mfma_f32_16x16x32_f16(Kh[kvt], Ql[qt], st[kvt][qt], 0, 0, 0);
      st[kvt][qt] = __builtin_amdgcn_mfma_f32_16x16x32_f16(Kl[kvt], Qh[qt], st[kvt][qt], 0, 0, 0);
    }

  const float ls = lsc[h];
  const float* rb = rpb + ((size_t)h << 12);
  float mx[4], sm[4], inv[4];
#pragma unroll
  for (int qt = 0; qt < 4; ++qt) {
    int qg = qt * 16 + l15;
    mx[qt] = -1e30f;
#pragma unroll
    for (int kvt = 0; kvt < 4; ++kvt) {
      f32x4 r4 = *(const f32x4*)(rb + qg * 64 + kvt * 16 + lq * 4);
#pragma unroll
      for (int r = 0; r < 4; ++r) {
        float z = st[kvt][qt][r] * ls + r4[r];
        st[kvt][qt][r] = z;
        mx[qt] = fmaxf(mx[qt], z);
      }
    }
    mx[qt] = fmaxf(mx[qt], __shfl_xor(mx[qt], 16));
    mx[qt] = fmaxf(mx[qt], __shfl_xor(mx[qt], 32));
    sm[qt] = 0.f;
#pragma unroll
    for (int kvt = 0; kvt < 4; ++kvt)
#pragma unroll
      for (int r = 0; r < 4; ++r) {
        float e = __expf(st[kvt][qt][r] - mx[qt]);
        st[kvt][qt][r] = e;
        sm[qt] += e;
      }
    sm[qt] += __shfl_xor(sm[qt], 16);
    sm[qt] += __shfl_xor(sm[qt], 32);
    inv[qt] = 1.f / sm[qt];
  }

#pragma unroll
  for (int qt = 0; qt < 4; ++qt) {
    int qg = qt * 16 + l15;
#pragma unroll
    for (int kvt = 0; kvt < 4; ++kvt)
#pragma unroll
      for (int p2 = 0; p2 < 2; ++p2) {
        float pa = st[kvt][qt][2 * p2] * inv[qt];
        float pc = st[kvt][qt][2 * p2 + 1] * inv[qt];
        half_t ha = (half_t)pa, hc = (half_t)pc;
        unsigned wh = h_bits(ha) | ((unsigned)h_bits(hc) << 16);
        unsigned wl = h_bits((half_t)(pa - (float)ha)) |
                      ((unsigned)h_bits((half_t)(pc - (float)hc)) << 16);
        int kv = kvt * 16 + lq * 4 + 2 * p2;
        pw[wid][0][qg * 36 + (kv >> 1)] = wh;
        pw[wid][1][qg * 36 + (kv >> 1)] = wl;
      }
  }

  half8 Vf[2][2];                          // [dt][ks]
#pragma unroll
  for (int dt = 0; dt < 2; ++dt)
#pragma unroll
    for (int ks = 0; ks < 2; ++ks)
      Vf[dt][ks] = *(const half8*)(vt + base + (dt * 16 + l15) * 64 + ks * 32 + lq * 8);
  f32x4 ot[2][4];                          // [dt][qt]
#pragma unroll
  for (int a = 0; a < 2; ++a)
#pragma unroll
    for (int b = 0; b < 4; ++b)
#pragma unroll
      for (int r = 0; r < 4; ++r) ot[a][b][r] = 0.f;
  const char* pb0 = (const char*)&pw[wid][0][0];
  const char* pb1 = (const char*)&pw[wid][1][0];
#pragma unroll
  for (int qt = 0; qt < 4; ++qt)
#pragma unroll
    for (int ks = 0; ks < 2; ++ks) {
      int off = (qt * 16 + l15) * 144 + ks * 64 + lq * 16;
      half8 Pf = *(const half8*)(pb0 + off);
      half8 Pl = *(const half8*)(pb1 + off);
#pragma unroll
      for (int dt = 0; dt < 2; ++dt) {
        ot[dt][qt] = __builtin_amdgcn_mfma_f32_16x16x32_f16(Vf[dt][ks], Pf, ot[dt][qt], 0, 0, 0);
        ot[dt][qt] = __builtin_amdgcn_mfma_f32_16x16x32_f16(Vf[dt][ks], Pl, ot[dt][qt], 0, 0, 0);
      }
    }

  int win = pair >> 4;
#pragma unroll
  for (int dt = 0; dt < 2; ++dt)
#pragma unroll
    for (int qt = 0; qt < 4; ++qt) {
      int t = win * 64 + qt * 16 + l15;
      int d0 = dt * 16 + lq * 4;
      ushort_t hb[4];
#pragma unroll
      for (int r = 0; r < 4; ++r) hb[r] = h_bits((half_t)ot[dt][qt][r]);
      *(uint2*)&oh[(size_t)t * 512 + h * 32 + d0] =
          make_uint2(hb[0] | ((unsigned)hb[1] << 16), hb[2] | ((unsigned)hb[3] << 16));
    }
}

// ---------------------------------------------------------------------------
extern "C" void kernel_launch(void* const* d_in, const int* in_sizes, int n_in,
                              void* d_out, int out_size, void* d_ws, size_t ws_size,
                              hipStream_t stream) {
  const float* x      = (const float*)d_in[0];
  const float* qkvw   = (const float*)d_in[1];
  const float* qb     = (const float*)d_in[2];
  const float* vb     = (const float*)d_in[3];
  const float* lsc    = (const float*)d_in[4];
  const float* w1     = (const float*)d_in[5];
  const float* b1     = (const float*)d_in[6];
  const float* w2     = (const float*)d_in[7];
  const float* pwt    = (const float*)d_in[8];
  const float* pb     = (const float*)d_in[9];
  const float* coords = (const float*)d_in[10];
  const int*   ridx   = (const int*)d_in[11];
  float* out = (float*)d_out;
  char* ws = (char*)d_ws;

  size_t off = 0;
  auto alloc = [&](size_t bytes) {
    size_t r = off;
    off = (off + bytes + 255) & ~(size_t)255;
    return r;
  };
  size_t oWQH = alloc((size_t)1536 * 512 * 2);
  size_t oWQL = alloc((size_t)1536 * 512 * 2);
  size_t oWPH = alloc((size_t)512 * 512 * 2);
  size_t oWPL = alloc((size_t)512 * 512 * 2);
  size_t oRPB = alloc((size_t)16 * 4096 * 4);
  size_t oTBL = alloc((size_t)225 * 16 * 4);
  size_t fixed = off;

  // per-slice planes: qh,ql,kh,kl,vt,ao = 6 * Ms*1024 bytes
  int S = 1;
  while (S <= 32) {
    size_t Ms = (size_t)MROWS / S;
    size_t need = fixed + Ms * 1024 * 6 + 4096;
    if (need <= ws_size) break;
    S <<= 1;
  }
  if (S > 64) S = 64;
  size_t Ms = (size_t)MROWS / S;

  size_t oQH = alloc(Ms * 1024);
  size_t oQL = alloc(Ms * 1024);
  size_t oKH = alloc(Ms * 1024);
  size_t oKL = alloc(Ms * 1024);
  size_t oVT = alloc(Ms * 1024);
  size_t oAO = alloc(Ms * 1024);

  ushort_t* wqh = (ushort_t*)(ws + oWQH);
  ushort_t* wql = (ushort_t*)(ws + oWQL);
  ushort_t* wph = (ushort_t*)(ws + oWPH);
  ushort_t* wpl = (ushort_t*)(ws + oWPL);
  float* rpb = (float*)(ws + oRPB);
  float* tbl = (float*)(ws + oTBL);
  ushort_t* qh = (ushort_t*)(ws + oQH);
  ushort_t* ql = (ushort_t*)(ws + oQL);
  ushort_t* kh = (ushort_t*)(ws + oKH);
  ushort_t* kl = (ushort_t*)(ws + oKL);
  ushort_t* vt = (ushort_t*)(ws + oVT);
  ushort_t* ao = (ushort_t*)(ws + oAO);

  k_split<<<768, 256, 0, stream>>>(qkvw, wqh, wql, 1536 * 512 / 4);
  k_split<<<256, 256, 0, stream>>>(pwt, wph, wpl, 512 * 512 / 4);
  k_cpb1<<<225, 256, 0, stream>>>(coords, w1, b1, w2, tbl);
  k_cpb2<<<256, 256, 0, stream>>>(tbl, ridx, rpb);

  int ntn256 = (int)(Ms / 256);
  int g0 = 12 * ntn256;
  int ntn = (int)(Ms / 128);
  int g1 = 4 * ntn;
  int ga = (int)((Ms / 64) * 16 / 2);

  for (int s = 0; s < S; ++s) {
    const float* xs = x + (size_t)s * Ms * 512;
    k_qkv<<<g0, 256, 0, stream>>>(wqh, wql, xs, qb, vb, qh, ql, kh, kl, vt);
    k_attn<<<ga, 128, 0, stream>>>(qh, ql, kh, kl, vt, rpb, lsc, ao);
    k_proj<<<g1, 256, 0, stream>>>(wph, wpl, ao, pb, out + (size_t)s * Ms * 512);
  }
  (void)in_sizes; (void)n_in; (void)out_size; (void)ws_size;
}

// Round 8
// 843.834 us; speedup vs baseline: 1.1755x; 1.1755x over previous
//
#include <hip/hip_runtime.h>
#include <hip/hip_bf16.h>
#include <stdint.h>
#include <stddef.h>

// ---------------------------------------------------------------------------
// Swin-V2 window attention, MI355X.  fp16-hi/lo ("fp16x2") everywhere.
// R8 = R5 structure (best known: qkv 495us) + 2-bit row-XOR LDS swizzle:
//   chunk' = chunk ^ (row&3) ^ ((row>>2)&3)
// applied to A staging (source pre-swizzle), B ds_writes, and all frag reads
// (k_qkv + k_proj). Kills the structural 4-way bank conflict (lr vs lr+4).
// R6/R7's B-direct-from-global experiment REGRESSED (TA-bound, 2KB-stride
// uncoalesced) and is reverted.
// ---------------------------------------------------------------------------

typedef unsigned short ushort_t;
typedef _Float16 half_t;
typedef __attribute__((ext_vector_type(8))) _Float16 half8;   // 4 VGPR
typedef __attribute__((ext_vector_type(4))) float f32x4;

#define MROWS 65536   // 1024 windows * 64 tokens

__device__ __forceinline__ ushort_t h_bits(half_t h) {
  union { half_t h; ushort_t u; } c; c.h = h; return c.u;
}

__device__ __forceinline__ void gload16(const void* g, void* l) {
  __builtin_amdgcn_global_load_lds(
      (const __attribute__((address_space(1))) unsigned int*)g,
      (__attribute__((address_space(3))) unsigned int*)l, 16, 0, 0);
}

// ---------------- split fp32 -> fp16 hi + fp16 lo (weights only) -----------
__global__ __launch_bounds__(256) void k_split(const float* __restrict__ src,
                                               ushort_t* __restrict__ hi,
                                               ushort_t* __restrict__ lo, int n4) {
  int stride = gridDim.x * blockDim.x;
  for (int i = blockIdx.x * blockDim.x + threadIdx.x; i < n4; i += stride) {
    f32x4 x = reinterpret_cast<const f32x4*>(src)[i];
    ushort_t h4[4], l4[4];
#pragma unroll
    for (int j = 0; j < 4; ++j) {
      half_t hh = (half_t)x[j];
      h4[j] = h_bits(hh);
      l4[j] = h_bits((half_t)(x[j] - (float)hh));
    }
    reinterpret_cast<uint2*>(hi)[i] =
        make_uint2(h4[0] | ((unsigned)h4[1] << 16), h4[2] | ((unsigned)h4[3] << 16));
    reinterpret_cast<uint2*>(lo)[i] =
        make_uint2(l4[0] | ((unsigned)l4[1] << 16), l4[2] | ((unsigned)l4[3] << 16));
  }
}

// ---------------- CPB MLP: 225 positions -> 16*sigmoid table ---------------
__global__ __launch_bounds__(256) void k_cpb1(const float* __restrict__ coords,
                                              const float* __restrict__ w1,
                                              const float* __restrict__ b1,
                                              const float* __restrict__ w2,
                                              float* __restrict__ tbl) {
  __shared__ float hid[512];
  int p = blockIdx.x;
  float c0 = coords[2 * p], c1 = coords[2 * p + 1];
  int t = threadIdx.x;
  for (int j = t; j < 512; j += 256) {
    float v = c0 * w1[2 * j] + c1 * w1[2 * j + 1] + b1[j];
    hid[j] = v > 0.f ? v : 0.f;
  }
  __syncthreads();
  int wid = t >> 6, lane = t & 63;
#pragma unroll
  for (int hh = 0; hh < 4; ++hh) {
    int head = wid * 4 + hh;
    float s = 0.f;
    for (int j = lane; j < 512; j += 64) s += hid[j] * w2[head * 512 + j];
#pragma unroll
    for (int off = 32; off > 0; off >>= 1) s += __shfl_xor(s, off);
    if (lane == 0) tbl[p * 16 + head] = 16.f / (1.f + __expf(-s));
  }
}

__global__ __launch_bounds__(256) void k_cpb2(const float* __restrict__ tbl,
                                              const int* __restrict__ ridx,
                                              float* __restrict__ rpb) {
  int idx = blockIdx.x * 256 + threadIdx.x;   // 65536 = 16 heads * 4096
  int h = idx >> 12, nm = idx & 4095;
  rpb[idx] = tbl[ridx[nm] * 16 + h];
}

// 2-bit row-XOR chunk swizzle (bijective per row; 2-way max bank aliasing)
__device__ __forceinline__ int swz(int c, int r) {
  return c ^ (r & 3) ^ ((r >> 2) & 3);
}

// ---------------- QKV GEMM: C[ch,tok] = W[ch,K] * X[tok,K]^T ---------------
// A = W fp16 hi/lo via global_load_lds; B = x fp32 reg-staged -> hi/lo LDS.
// Per K-step (32): 48 MFMAs (AhBh + AhBl + AlBh). 16 K-steps.
__global__ __launch_bounds__(256, 2) void k_qkv(
    const ushort_t* __restrict__ Wh, const ushort_t* __restrict__ Wl,
    const float* __restrict__ X,
    const float* __restrict__ qb, const float* __restrict__ vb,
    ushort_t* __restrict__ oqh, ushort_t* __restrict__ oql,
    ushort_t* __restrict__ okh, ushort_t* __restrict__ okl,
    ushort_t* __restrict__ ovt) {
  __shared__ ushort_t lAh[2][4096];
  __shared__ ushort_t lAl[2][4096];
  __shared__ ushort_t lBh[2][4096];
  __shared__ ushort_t lBl[2][4096];

  int nwg = gridDim.x, bid = blockIdx.x;
  int idx = ((nwg & 7) == 0) ? ((bid & 7) * (nwg >> 3) + (bid >> 3)) : bid;
  int tm = idx % 12, tn = idx / 12;    // 12 consecutive idx share tn (x L2 reuse)
  int tid = threadIdx.x;
  int wid = tid >> 6, lane = tid & 63;
  int wr = wid >> 1, wc = wid & 1;
  int lr = lane & 15, lq = lane >> 4;

  // A staging: per-thread source chunk pre-swizzled; linear LDS dest.
  // (row+64 keeps the same swizzle: bits 0-3 of row unchanged by +64.)
  int rA = tid >> 2, qA = tid & 3;
  size_t gA = (size_t)(tm * 128 + rA) * 512 + (swz(qA, rA) << 3);
  int dA = wid * 512;

  // B reg-stage: 4 sweeps; thread owns (row = s*32 + rB, cols qB*4..+3)
  int rB = tid >> 3, qB = tid & 7;
  const float* gB = X + (size_t)(tn * 128 + rB) * 512 + qB * 4;  // + s*16384 + kk
  int dB = rB * 32 + (swz(qB >> 1, rB) << 3) + ((qB & 1) << 2);  // + s*1024

  f32x4 acc[4][4];
#pragma unroll
  for (int i = 0; i < 4; ++i)
#pragma unroll
    for (int j = 0; j < 4; ++j)
#pragma unroll
      for (int r = 0; r < 4; ++r) acc[i][j][r] = 0.f;

  auto stageA = [&](int kk, int bs) {
    gload16(Wh + gA + kk, &lAh[bs][dA]);
    gload16(Wh + gA + 32768 + kk, &lAh[bs][2048 + dA]);
    gload16(Wl + gA + kk, &lAl[bs][dA]);
    gload16(Wl + gA + 32768 + kk, &lAl[bs][2048 + dA]);
  };
  auto loadB = [&](int kk, f32x4* xr) {
#pragma unroll
    for (int s = 0; s < 4; ++s) xr[s] = *(const f32x4*)(gB + s * 16384 + kk);
  };
  auto writeB = [&](const f32x4* xr, int bs) {
#pragma unroll
    for (int s = 0; s < 4; ++s) {
      ushort_t h4[4], l4[4];
#pragma unroll
      for (int e = 0; e < 4; ++e) {
        half_t hh = (half_t)xr[s][e];
        h4[e] = h_bits(hh);
        l4[e] = h_bits((half_t)(xr[s][e] - (float)hh));
      }
      *(uint2*)&lBh[bs][dB + s * 1024] =
          make_uint2(h4[0] | ((unsigned)h4[1] << 16), h4[2] | ((unsigned)h4[3] << 16));
      *(uint2*)&lBl[bs][dB + s * 1024] =
          make_uint2(l4[0] | ((unsigned)l4[1] << 16), l4[2] | ((unsigned)l4[3] << 16));
    }
  };

  f32x4 xr[4];
  stageA(0, 0);
  loadB(0, xr);
  writeB(xr, 0);
  const int c16 = swz(lq, lr) << 3;   // read-side inverse swizzle
#pragma unroll 2
  for (int t = 0; t < 16; ++t) {
    __syncthreads();
    int bs = t & 1;
    if (t < 15) {
      stageA((t + 1) * 32, bs ^ 1);
      loadB((t + 1) * 32, xr);
    }
    half8 ah[4], al[4], bh[4], bl[4];
#pragma unroll
    for (int i = 0; i < 4; ++i) {
      int ro = (wr * 64 + i * 16 + lr) * 32 + c16;
      ah[i] = *(const half8*)&lAh[bs][ro];
      al[i] = *(const half8*)&lAl[bs][ro];
    }
#pragma unroll
    for (int j = 0; j < 4; ++j) {
      int ro = (wc * 64 + j * 16 + lr) * 32 + c16;
      bh[j] = *(const half8*)&lBh[bs][ro];
      bl[j] = *(const half8*)&lBl[bs][ro];
    }
#pragma unroll
    for (int i = 0; i < 4; ++i)
#pragma unroll
      for (int j = 0; j < 4; ++j) {
        acc[i][j] = __builtin_amdgcn_mfma_f32_16x16x32_f16(ah[i], bh[j], acc[i][j], 0, 0, 0);
        acc[i][j] = __builtin_amdgcn_mfma_f32_16x16x32_f16(ah[i], bl[j], acc[i][j], 0, 0, 0);
        acc[i][j] = __builtin_amdgcn_mfma_f32_16x16x32_f16(al[i], bh[j], acc[i][j], 0, 0, 0);
      }
    if (t < 15) writeB(xr, bs ^ 1);
  }

  // C layout: col = lane&15 (token), row = (lane>>4)*4 + reg (channel)
#pragma unroll
  for (int i = 0; i < 4; ++i) {
    int ch0 = tm * 128 + wr * 64 + i * 16 + lq * 4;
#pragma unroll
    for (int j = 0; j < 4; ++j) {
      int tok = tn * 128 + wc * 64 + j * 16 + lr;
      int sec = tm >> 2;                 // block-uniform: 0=q,1=k,2=v
      int h = (ch0 >> 5) & 15, d0 = ch0 & 31;
      int win = tok >> 6, n = tok & 63;
      size_t pr = (size_t)win * 16 + h;
      f32x4 b4;
      if (sec == 0)      b4 = *(const f32x4*)&qb[ch0];
      else if (sec == 2) b4 = *(const f32x4*)&vb[ch0 - 1024];
      else { b4[0] = 0.f; b4[1] = 0.f; b4[2] = 0.f; b4[3] = 0.f; }
      if (sec == 2) {
#pragma unroll
        for (int r = 0; r < 4; ++r) {
          float v = acc[i][j][r] + b4[r];
          ovt[(pr * 32 + d0 + r) * 64 + n] = h_bits((half_t)v);
        }
      } else {
        ushort_t hb[4], lb4[4];
#pragma unroll
        for (int r = 0; r < 4; ++r) {
          float v = acc[i][j][r] + b4[r];
          half_t hh = (half_t)v;
          hb[r] = h_bits(hh);
          lb4[r] = h_bits((half_t)(v - (float)hh));
        }
        uint2 hw = make_uint2(hb[0] | ((unsigned)hb[1] << 16), hb[2] | ((unsigned)hb[3] << 16));
        uint2 lw = make_uint2(lb4[0] | ((unsigned)lb4[1] << 16), lb4[2] | ((unsigned)lb4[3] << 16));
        size_t o = (pr * 64 + n) * 32 + d0;
        if (sec == 0) { *(uint2*)&oqh[o] = hw; *(uint2*)&oql[o] = lw; }
        else          { *(uint2*)&okh[o] = hw; *(uint2*)&okl[o] = lw; }
      }
    }
  }
}

// ---------------- proj GEMM: C[ch,tok] = W[ch,K] * AO[tok,K]^T -------------
// A = Wp hi/lo co-resident; B = attn-out fp16 (hi only). 32 MFMA / barrier.
__global__ __launch_bounds__(256, 2) void k_proj(
    const ushort_t* __restrict__ Wh, const ushort_t* __restrict__ Wl,
    const ushort_t* __restrict__ Bp,
    const float* __restrict__ pb, float* __restrict__ outp) {
  __shared__ ushort_t lAh[2][4096];
  __shared__ ushort_t lAl[2][4096];
  __shared__ ushort_t lBh[2][4096];

  int nwg = gridDim.x, bid = blockIdx.x;
  int idx = ((nwg & 7) == 0) ? ((bid & 7) * (nwg >> 3) + (bid >> 3)) : bid;
  int tm = idx % 4, tn = idx / 4;
  int tid = threadIdx.x;
  int wid = tid >> 6, lane = tid & 63;
  int wr = wid >> 1, wc = wid & 1;
  int lr = lane & 15, lq = lane >> 4;

  int rA = tid >> 2, qA = tid & 3;
  int sw = swz(qA, rA) << 3;
  size_t gA = (size_t)(tm * 128 + rA) * 512 + sw;
  size_t gB = (size_t)(tn * 128 + rA) * 512 + sw;
  int dA = wid * 512;

  f32x4 acc[4][4];
#pragma unroll
  for (int i = 0; i < 4; ++i)
#pragma unroll
    for (int j = 0; j < 4; ++j)
#pragma unroll
      for (int r = 0; r < 4; ++r) acc[i][j][r] = 0.f;

  auto stage = [&](int kk, int bs) {
    gload16(Wh + gA + kk, &lAh[bs][dA]);
    gload16(Wh + gA + 32768 + kk, &lAh[bs][2048 + dA]);
    gload16(Wl + gA + kk, &lAl[bs][dA]);
    gload16(Wl + gA + 32768 + kk, &lAl[bs][2048 + dA]);
    gload16(Bp + gB + kk, &lBh[bs][dA]);
    gload16(Bp + gB + 32768 + kk, &lBh[bs][2048 + dA]);
  };

  stage(0, 0);
  const int c16 = swz(lq, lr) << 3;
#pragma unroll 2
  for (int t = 0; t < 16; ++t) {
    __syncthreads();
    int bs = t & 1;
    if (t < 15) stage((t + 1) * 32, bs ^ 1);
    half8 ah[4], al[4], bh[4];
#pragma unroll
    for (int i = 0; i < 4; ++i) {
      int ro = (wr * 64 + i * 16 + lr) * 32 + c16;
      ah[i] = *(const half8*)&lAh[bs][ro];
      al[i] = *(const half8*)&lAl[bs][ro];
    }
#pragma unroll
    for (int j = 0; j < 4; ++j)
      bh[j] = *(const half8*)&lBh[bs][(wc * 64 + j * 16 + lr) * 32 + c16];
#pragma unroll
    for (int i = 0; i < 4; ++i)
#pragma unroll
      for (int j = 0; j < 4; ++j) {
        acc[i][j] = __builtin_amdgcn_mfma_f32_16x16x32_f16(ah[i], bh[j], acc[i][j], 0, 0, 0);
        acc[i][j] = __builtin_amdgcn_mfma_f32_16x16x32_f16(al[i], bh[j], acc[i][j], 0, 0, 0);
      }
  }

#pragma unroll
  for (int i = 0; i < 4; ++i) {
    int ch0 = tm * 128 + wr * 64 + i * 16 + lq * 4;
    f32x4 b4 = *(const f32x4*)&pb[ch0];
#pragma unroll
    for (int j = 0; j < 4; ++j) {
      int tok = tn * 128 + wc * 64 + j * 16 + lr;
      f32x4 o;
#pragma unroll
      for (int r = 0; r < 4; ++r) o[r] = acc[i][j][r] + b4[r];
      *(f32x4*)&outp[(size_t)tok * 512 + ch0] = o;
    }
  }
}

// ---------------- MFMA attention: 1 wave per (window,head) -----------------
__global__ __launch_bounds__(128) void k_attn(
    const ushort_t* __restrict__ qph, const ushort_t* __restrict__ qpl,
    const ushort_t* __restrict__ kph, const ushort_t* __restrict__ kpl,
    const ushort_t* __restrict__ vt,
    const float* __restrict__ rpb, const float* __restrict__ lsc,
    ushort_t* __restrict__ oh) {
  __shared__ unsigned pw[2][2][64 * 36];   // [wave][P hi/lo][q row * 36 words]
  const int tid = threadIdx.x;
  const int wid = tid >> 6, lane = tid & 63;
  const int pair = blockIdx.x * 2 + wid;   // window*16 + head
  const int h = pair & 15;
  const int l15 = lane & 15, lq = lane >> 4;
  const size_t base = (size_t)pair * 2048;

  half8 Kh[4], Kl[4], Qh[4], Ql[4];
#pragma unroll
  for (int t4 = 0; t4 < 4; ++t4) {
    int off = (t4 * 16 + l15) * 32 + lq * 8;
    Kh[t4] = *(const half8*)(kph + base + off);
    Kl[t4] = *(const half8*)(kpl + base + off);
    Qh[t4] = *(const half8*)(qph + base + off);
    Ql[t4] = *(const half8*)(qpl + base + off);
  }
  f32x4 st[4][4];                          // [kvt][qt]
#pragma unroll
  for (int a = 0; a < 4; ++a)
#pragma unroll
    for (int b = 0; b < 4; ++b)
#pragma unroll
      for (int r = 0; r < 4; ++r) st[a][b][r] = 0.f;
#pragma unroll
  for (int kvt = 0; kvt < 4; ++kvt)
#pragma unroll
    for (int qt = 0; qt < 4; ++qt) {
      st[kvt][qt] = __builtin_amdgcn_mfma_f32_16x16x32_f16(Kh[kvt], Qh[qt], st[kvt][qt], 0, 0, 0);
      st[kvt][qt] = __builtin_amdgcn_mfma_f32_16x16x32_f16(Kh[kvt], Ql[qt], st[kvt][qt], 0, 0, 0);
      st[kvt][qt] = __builtin_amdgcn_mfma_f32_16x16x32_f16(Kl[kvt], Qh[qt], st[kvt][qt], 0, 0, 0);
    }

  const float ls = lsc[h];
  const float* rb = rpb + ((size_t)h << 12);
  float mx[4], sm[4], inv[4];
#pragma unroll
  for (int qt = 0; qt < 4; ++qt) {
    int qg = qt * 16 + l15;
    mx[qt] = -1e30f;
#pragma unroll
    for (int kvt = 0; kvt < 4; ++kvt) {
      f32x4 r4 = *(const f32x4*)(rb + qg * 64 + kvt * 16 + lq * 4);
#pragma unroll
      for (int r = 0; r < 4; ++r) {
        float z = st[kvt][qt][r] * ls + r4[r];
        st[kvt][qt][r] = z;
        mx[qt] = fmaxf(mx[qt], z);
      }
    }
    mx[qt] = fmaxf(mx[qt], __shfl_xor(mx[qt], 16));
    mx[qt] = fmaxf(mx[qt], __shfl_xor(mx[qt], 32));
    sm[qt] = 0.f;
#pragma unroll
    for (int kvt = 0; kvt < 4; ++kvt)
#pragma unroll
      for (int r = 0; r < 4; ++r) {
        float e = __expf(st[kvt][qt][r] - mx[qt]);
        st[kvt][qt][r] = e;
        sm[qt] += e;
      }
    sm[qt] += __shfl_xor(sm[qt], 16);
    sm[qt] += __shfl_xor(sm[qt], 32);
    inv[qt] = 1.f / sm[qt];
  }

#pragma unroll
  for (int qt = 0; qt < 4; ++qt) {
    int qg = qt * 16 + l15;
#pragma unroll
    for (int kvt = 0; kvt < 4; ++kvt)
#pragma unroll
      for (int p2 = 0; p2 < 2; ++p2) {
        float pa = st[kvt][qt][2 * p2] * inv[qt];
        float pc = st[kvt][qt][2 * p2 + 1] * inv[qt];
        half_t ha = (half_t)pa, hc = (half_t)pc;
        unsigned wh = h_bits(ha) | ((unsigned)h_bits(hc) << 16);
        unsigned wl = h_bits((half_t)(pa - (float)ha)) |
                      ((unsigned)h_bits((half_t)(pc - (float)hc)) << 16);
        int kv = kvt * 16 + lq * 4 + 2 * p2;
        pw[wid][0][qg * 36 + (kv >> 1)] = wh;
        pw[wid][1][qg * 36 + (kv >> 1)] = wl;
      }
  }

  half8 Vf[2][2];                          // [dt][ks]
#pragma unroll
  for (int dt = 0; dt < 2; ++dt)
#pragma unroll
    for (int ks = 0; ks < 2; ++ks)
      Vf[dt][ks] = *(const half8*)(vt + base + (dt * 16 + l15) * 64 + ks * 32 + lq * 8);
  f32x4 ot[2][4];                          // [dt][qt]
#pragma unroll
  for (int a = 0; a < 2; ++a)
#pragma unroll
    for (int b = 0; b < 4; ++b)
#pragma unroll
      for (int r = 0; r < 4; ++r) ot[a][b][r] = 0.f;
  const char* pb0 = (const char*)&pw[wid][0][0];
  const char* pb1 = (const char*)&pw[wid][1][0];
#pragma unroll
  for (int qt = 0; qt < 4; ++qt)
#pragma unroll
    for (int ks = 0; ks < 2; ++ks) {
      int off = (qt * 16 + l15) * 144 + ks * 64 + lq * 16;
      half8 Pf = *(const half8*)(pb0 + off);
      half8 Pl = *(const half8*)(pb1 + off);
#pragma unroll
      for (int dt = 0; dt < 2; ++dt) {
        ot[dt][qt] = __builtin_amdgcn_mfma_f32_16x16x32_f16(Vf[dt][ks], Pf, ot[dt][qt], 0, 0, 0);
        ot[dt][qt] = __builtin_amdgcn_mfma_f32_16x16x32_f16(Vf[dt][ks], Pl, ot[dt][qt], 0, 0, 0);
      }
    }

  int win = pair >> 4;
#pragma unroll
  for (int dt = 0; dt < 2; ++dt)
#pragma unroll
    for (int qt = 0; qt < 4; ++qt) {
      int t = win * 64 + qt * 16 + l15;
      int d0 = dt * 16 + lq * 4;
      ushort_t hb[4];
#pragma unroll
      for (int r = 0; r < 4; ++r) hb[r] = h_bits((half_t)ot[dt][qt][r]);
      *(uint2*)&oh[(size_t)t * 512 + h * 32 + d0] =
          make_uint2(hb[0] | ((unsigned)hb[1] << 16), hb[2] | ((unsigned)hb[3] << 16));
    }
}

// ---------------------------------------------------------------------------
extern "C" void kernel_launch(void* const* d_in, const int* in_sizes, int n_in,
                              void* d_out, int out_size, void* d_ws, size_t ws_size,
                              hipStream_t stream) {
  const float* x      = (const float*)d_in[0];
  const float* qkvw   = (const float*)d_in[1];
  const float* qb     = (const float*)d_in[2];
  const float* vb     = (const float*)d_in[3];
  const float* lsc    = (const float*)d_in[4];
  const float* w1     = (const float*)d_in[5];
  const float* b1     = (const float*)d_in[6];
  const float* w2     = (const float*)d_in[7];
  const float* pwt    = (const float*)d_in[8];
  const float* pb     = (const float*)d_in[9];
  const float* coords = (const float*)d_in[10];
  const int*   ridx   = (const int*)d_in[11];
  float* out = (float*)d_out;
  char* ws = (char*)d_ws;

  size_t off = 0;
  auto alloc = [&](size_t bytes) {
    size_t r = off;
    off = (off + bytes + 255) & ~(size_t)255;
    return r;
  };
  size_t oWQH = alloc((size_t)1536 * 512 * 2);
  size_t oWQL = alloc((size_t)1536 * 512 * 2);
  size_t oWPH = alloc((size_t)512 * 512 * 2);
  size_t oWPL = alloc((size_t)512 * 512 * 2);
  size_t oRPB = alloc((size_t)16 * 4096 * 4);
  size_t oTBL = alloc((size_t)225 * 16 * 4);
  size_t fixed = off;

  // per-slice planes: qh,ql,kh,kl,vt,ao = 6 * Ms*1024 bytes
  int S = 1;
  while (S <= 32) {
    size_t Ms = (size_t)MROWS / S;
    size_t need = fixed + Ms * 1024 * 6 + 4096;
    if (need <= ws_size) break;
    S <<= 1;
  }
  if (S > 64) S = 64;
  size_t Ms = (size_t)MROWS / S;

  size_t oQH = alloc(Ms * 1024);
  size_t oQL = alloc(Ms * 1024);
  size_t oKH = alloc(Ms * 1024);
  size_t oKL = alloc(Ms * 1024);
  size_t oVT = alloc(Ms * 1024);
  size_t oAO = alloc(Ms * 1024);

  ushort_t* wqh = (ushort_t*)(ws + oWQH);
  ushort_t* wql = (ushort_t*)(ws + oWQL);
  ushort_t* wph = (ushort_t*)(ws + oWPH);
  ushort_t* wpl = (ushort_t*)(ws + oWPL);
  float* rpb = (float*)(ws + oRPB);
  float* tbl = (float*)(ws + oTBL);
  ushort_t* qh = (ushort_t*)(ws + oQH);
  ushort_t* ql = (ushort_t*)(ws + oQL);
  ushort_t* kh = (ushort_t*)(ws + oKH);
  ushort_t* kl = (ushort_t*)(ws + oKL);
  ushort_t* vt = (ushort_t*)(ws + oVT);
  ushort_t* ao = (ushort_t*)(ws + oAO);

  k_split<<<768, 256, 0, stream>>>(qkvw, wqh, wql, 1536 * 512 / 4);
  k_split<<<256, 256, 0, stream>>>(pwt, wph, wpl, 512 * 512 / 4);
  k_cpb1<<<225, 256, 0, stream>>>(coords, w1, b1, w2, tbl);
  k_cpb2<<<256, 256, 0, stream>>>(tbl, ridx, rpb);

  int ntn = (int)(Ms / 128);
  int g0 = 12 * ntn;
  int g1 = 4 * ntn;
  int ga = (int)((Ms / 64) * 16 / 2);

  for (int s = 0; s < S; ++s) {
    const float* xs = x + (size_t)s * Ms * 512;
    k_qkv<<<g0, 256, 0, stream>>>(wqh, wql, xs, qb, vb, qh, ql, kh, kl, vt);
    k_attn<<<ga, 128, 0, stream>>>(qh, ql, kh, kl, vt, rpb, lsc, ao);
    k_proj<<<g1, 256, 0, stream>>>(wph, wpl, ao, pb, out + (size_t)s * Ms * 512);
  }
  (void)in_sizes; (void)n_in; (void)out_size; (void)ws_size;
}

// Round 9
// 728.157 us; speedup vs baseline: 1.3622x; 1.1589x over previous
//
#include <hip/hip_runtime.h>
#include <hip/hip_bf16.h>
#include <stdint.h>
#include <stddef.h>

// ---------------------------------------------------------------------------
// Swin-V2 window attention, MI355X.  fp16-hi/lo pipeline.
// R9: precision-budget rebalance + occupancy.
//  - k_qkv: 2 phases (Ah*Bh + Al*Bh) — x-lo phase dropped (contributes only
//    ~4e-3 to logits vs 0.031 measured absmax). A: one plane per phase,
//    B: hi only -> LDS 32KB -> 4-5 blocks/CU (was 2). setprio on MFMA.
//  - k_proj: plain fp16 (W-lo dropped, ~3e-3 on out). LDS 32KB.
//  - k_attn: UNCHANGED (q/k hi+lo 3-phase QK^T, P hi/lo, V hi) — it is the
//    dominant error source and stays frozen.
// ---------------------------------------------------------------------------

typedef unsigned short ushort_t;
typedef _Float16 half_t;
typedef __attribute__((ext_vector_type(8))) _Float16 half8;   // 4 VGPR
typedef __attribute__((ext_vector_type(4))) float f32x4;

#define MROWS 65536   // 1024 windows * 64 tokens

__device__ __forceinline__ ushort_t h_bits(half_t h) {
  union { half_t h; ushort_t u; } c; c.h = h; return c.u;
}

__device__ __forceinline__ void gload16(const void* g, void* l) {
  __builtin_amdgcn_global_load_lds(
      (const __attribute__((address_space(1))) unsigned int*)g,
      (__attribute__((address_space(3))) unsigned int*)l, 16, 0, 0);
}

// ---------------- split fp32 -> fp16 hi + fp16 lo (qkv weights) ------------
__global__ __launch_bounds__(256) void k_split(const float* __restrict__ src,
                                               ushort_t* __restrict__ hi,
                                               ushort_t* __restrict__ lo, int n4) {
  int stride = gridDim.x * blockDim.x;
  for (int i = blockIdx.x * blockDim.x + threadIdx.x; i < n4; i += stride) {
    f32x4 x = reinterpret_cast<const f32x4*>(src)[i];
    ushort_t h4[4], l4[4];
#pragma unroll
    for (int j = 0; j < 4; ++j) {
      half_t hh = (half_t)x[j];
      h4[j] = h_bits(hh);
      l4[j] = h_bits((half_t)(x[j] - (float)hh));
    }
    reinterpret_cast<uint2*>(hi)[i] =
        make_uint2(h4[0] | ((unsigned)h4[1] << 16), h4[2] | ((unsigned)h4[3] << 16));
    reinterpret_cast<uint2*>(lo)[i] =
        make_uint2(l4[0] | ((unsigned)l4[1] << 16), l4[2] | ((unsigned)l4[3] << 16));
  }
}

// hi-only split for proj weight
__global__ __launch_bounds__(256) void k_split_h(const float* __restrict__ src,
                                                 ushort_t* __restrict__ hi, int n4) {
  int stride = gridDim.x * blockDim.x;
  for (int i = blockIdx.x * blockDim.x + threadIdx.x; i < n4; i += stride) {
    f32x4 x = reinterpret_cast<const f32x4*>(src)[i];
    ushort_t h4[4];
#pragma unroll
    for (int j = 0; j < 4; ++j) h4[j] = h_bits((half_t)x[j]);
    reinterpret_cast<uint2*>(hi)[i] =
        make_uint2(h4[0] | ((unsigned)h4[1] << 16), h4[2] | ((unsigned)h4[3] << 16));
  }
}

// ---------------- CPB MLP: 225 positions -> 16*sigmoid table ---------------
__global__ __launch_bounds__(256) void k_cpb1(const float* __restrict__ coords,
                                              const float* __restrict__ w1,
                                              const float* __restrict__ b1,
                                              const float* __restrict__ w2,
                                              float* __restrict__ tbl) {
  __shared__ float hid[512];
  int p = blockIdx.x;
  float c0 = coords[2 * p], c1 = coords[2 * p + 1];
  int t = threadIdx.x;
  for (int j = t; j < 512; j += 256) {
    float v = c0 * w1[2 * j] + c1 * w1[2 * j + 1] + b1[j];
    hid[j] = v > 0.f ? v : 0.f;
  }
  __syncthreads();
  int wid = t >> 6, lane = t & 63;
#pragma unroll
  for (int hh = 0; hh < 4; ++hh) {
    int head = wid * 4 + hh;
    float s = 0.f;
    for (int j = lane; j < 512; j += 64) s += hid[j] * w2[head * 512 + j];
#pragma unroll
    for (int off = 32; off > 0; off >>= 1) s += __shfl_xor(s, off);
    if (lane == 0) tbl[p * 16 + head] = 16.f / (1.f + __expf(-s));
  }
}

__global__ __launch_bounds__(256) void k_cpb2(const float* __restrict__ tbl,
                                              const int* __restrict__ ridx,
                                              float* __restrict__ rpb) {
  int idx = blockIdx.x * 256 + threadIdx.x;   // 65536 = 16 heads * 4096
  int h = idx >> 12, nm = idx & 4095;
  rpb[idx] = tbl[ridx[nm] * 16 + h];
}

// 2-bit row-XOR chunk swizzle (kept from R8; harmless)
__device__ __forceinline__ int swz(int c, int r) {
  return c ^ (r & 3) ^ ((r >> 2) & 3);
}

// ---------------- QKV GEMM: C[ch,tok] = W[ch,K] * X[tok,K]^T ---------------
// 2 phases: t=0..15 Ah*Bh, t=16..31 Al*Bh. One A plane resident per iter;
// B = x fp32 reg-staged -> fp16-hi LDS. 16 MFMA / barrier, LDS 32KB.
__global__ __launch_bounds__(256, 4) void k_qkv(
    const ushort_t* __restrict__ Wh, const ushort_t* __restrict__ Wl,
    const float* __restrict__ X,
    const float* __restrict__ qb, const float* __restrict__ vb,
    ushort_t* __restrict__ oqh, ushort_t* __restrict__ oql,
    ushort_t* __restrict__ okh, ushort_t* __restrict__ okl,
    ushort_t* __restrict__ ovt) {
  __shared__ ushort_t lA[2][4096];
  __shared__ ushort_t lB[2][4096];

  int nwg = gridDim.x, bid = blockIdx.x;
  int idx = ((nwg & 7) == 0) ? ((bid & 7) * (nwg >> 3) + (bid >> 3)) : bid;
  int tm = idx % 12, tn = idx / 12;    // 12 consecutive idx share tn (x L2 reuse)
  int tid = threadIdx.x;
  int wid = tid >> 6, lane = tid & 63;
  int wr = wid >> 1, wc = wid & 1;
  int lr = lane & 15, lq = lane >> 4;

  // A staging: source chunk pre-swizzled; linear LDS dest (2 sweeps: rows rA, rA+64)
  int rA = tid >> 2, qA = tid & 3;
  size_t gA = (size_t)(tm * 128 + rA) * 512 + (swz(qA, rA) << 3);
  int dA = wid * 512;

  // B reg-stage: 4 sweeps; thread owns (row = s*32 + rB, cols qB*4..+3)
  int rB = tid >> 3, qB = tid & 7;
  const float* gB = X + (size_t)(tn * 128 + rB) * 512 + qB * 4;
  int dB = rB * 32 + (swz(qB >> 1, rB) << 3) + ((qB & 1) << 2);

  f32x4 acc[4][4];
#pragma unroll
  for (int i = 0; i < 4; ++i)
#pragma unroll
    for (int j = 0; j < 4; ++j)
#pragma unroll
      for (int r = 0; r < 4; ++r) acc[i][j][r] = 0.f;

  auto stageA = [&](int t2, int bs) {
    int kk = (t2 & 15) * 32;
    const ushort_t* W = (t2 >= 16) ? Wl : Wh;
    gload16(W + gA + kk, &lA[bs][dA]);
    gload16(W + gA + 32768 + kk, &lA[bs][2048 + dA]);
  };
  auto loadB = [&](int t2, f32x4* xr) {
    int kk = (t2 & 15) * 32;
#pragma unroll
    for (int s = 0; s < 4; ++s) xr[s] = *(const f32x4*)(gB + s * 16384 + kk);
  };
  auto writeB = [&](const f32x4* xr, int bs) {
#pragma unroll
    for (int s = 0; s < 4; ++s) {
      ushort_t h4[4];
#pragma unroll
      for (int e = 0; e < 4; ++e) h4[e] = h_bits((half_t)xr[s][e]);
      *(uint2*)&lB[bs][dB + s * 1024] =
          make_uint2(h4[0] | ((unsigned)h4[1] << 16), h4[2] | ((unsigned)h4[3] << 16));
    }
  };

  f32x4 xr[4];
  stageA(0, 0);
  loadB(0, xr);
  writeB(xr, 0);
  const int c16 = swz(lq, lr) << 3;   // read-side inverse swizzle
#pragma unroll 2
  for (int t = 0; t < 32; ++t) {
    __syncthreads();
    int bs = t & 1;
    if (t < 31) {
      stageA(t + 1, bs ^ 1);
      loadB(t + 1, xr);
    }
    half8 af[4], bf[4];
#pragma unroll
    for (int i = 0; i < 4; ++i)
      af[i] = *(const half8*)&lA[bs][(wr * 64 + i * 16 + lr) * 32 + c16];
#pragma unroll
    for (int j = 0; j < 4; ++j)
      bf[j] = *(const half8*)&lB[bs][(wc * 64 + j * 16 + lr) * 32 + c16];
    __builtin_amdgcn_s_setprio(1);
#pragma unroll
    for (int i = 0; i < 4; ++i)
#pragma unroll
      for (int j = 0; j < 4; ++j)
        acc[i][j] = __builtin_amdgcn_mfma_f32_16x16x32_f16(af[i], bf[j], acc[i][j], 0, 0, 0);
    __builtin_amdgcn_s_setprio(0);
    if (t < 31) writeB(xr, bs ^ 1);
  }

  // C layout: col = lane&15 (token), row = (lane>>4)*4 + reg (channel)
#pragma unroll
  for (int i = 0; i < 4; ++i) {
    int ch0 = tm * 128 + wr * 64 + i * 16 + lq * 4;
#pragma unroll
    for (int j = 0; j < 4; ++j) {
      int tok = tn * 128 + wc * 64 + j * 16 + lr;
      int sec = tm >> 2;                 // block-uniform: 0=q,1=k,2=v
      int h = (ch0 >> 5) & 15, d0 = ch0 & 31;
      int win = tok >> 6, n = tok & 63;
      size_t pr = (size_t)win * 16 + h;
      f32x4 b4;
      if (sec == 0)      b4 = *(const f32x4*)&qb[ch0];
      else if (sec == 2) b4 = *(const f32x4*)&vb[ch0 - 1024];
      else { b4[0] = 0.f; b4[1] = 0.f; b4[2] = 0.f; b4[3] = 0.f; }
      if (sec == 2) {
#pragma unroll
        for (int r = 0; r < 4; ++r) {
          float v = acc[i][j][r] + b4[r];
          ovt[(pr * 32 + d0 + r) * 64 + n] = h_bits((half_t)v);
        }
      } else {
        ushort_t hb[4], lb4[4];
#pragma unroll
        for (int r = 0; r < 4; ++r) {
          float v = acc[i][j][r] + b4[r];
          half_t hh = (half_t)v;
          hb[r] = h_bits(hh);
          lb4[r] = h_bits((half_t)(v - (float)hh));
        }
        uint2 hw = make_uint2(hb[0] | ((unsigned)hb[1] << 16), hb[2] | ((unsigned)hb[3] << 16));
        uint2 lw = make_uint2(lb4[0] | ((unsigned)lb4[1] << 16), lb4[2] | ((unsigned)lb4[3] << 16));
        size_t o = (pr * 64 + n) * 32 + d0;
        if (sec == 0) { *(uint2*)&oqh[o] = hw; *(uint2*)&oql[o] = lw; }
        else          { *(uint2*)&okh[o] = hw; *(uint2*)&okl[o] = lw; }
      }
    }
  }
}

// ---------------- proj GEMM: plain fp16, C = Wp * AO^T ---------------------
__global__ __launch_bounds__(256, 4) void k_proj(
    const ushort_t* __restrict__ Wh,
    const ushort_t* __restrict__ Bp,
    const float* __restrict__ pb, float* __restrict__ outp) {
  __shared__ ushort_t lA[2][4096];
  __shared__ ushort_t lB[2][4096];

  int nwg = gridDim.x, bid = blockIdx.x;
  int idx = ((nwg & 7) == 0) ? ((bid & 7) * (nwg >> 3) + (bid >> 3)) : bid;
  int tm = idx % 4, tn = idx / 4;
  int tid = threadIdx.x;
  int wid = tid >> 6, lane = tid & 63;
  int wr = wid >> 1, wc = wid & 1;
  int lr = lane & 15, lq = lane >> 4;

  int rA = tid >> 2, qA = tid & 3;
  int sw = swz(qA, rA) << 3;
  size_t gA = (size_t)(tm * 128 + rA) * 512 + sw;
  size_t gB = (size_t)(tn * 128 + rA) * 512 + sw;
  int dA = wid * 512;

  f32x4 acc[4][4];
#pragma unroll
  for (int i = 0; i < 4; ++i)
#pragma unroll
    for (int j = 0; j < 4; ++j)
#pragma unroll
      for (int r = 0; r < 4; ++r) acc[i][j][r] = 0.f;

  auto stage = [&](int kk, int bs) {
    gload16(Wh + gA + kk, &lA[bs][dA]);
    gload16(Wh + gA + 32768 + kk, &lA[bs][2048 + dA]);
    gload16(Bp + gB + kk, &lB[bs][dA]);
    gload16(Bp + gB + 32768 + kk, &lB[bs][2048 + dA]);
  };

  stage(0, 0);
  const int c16 = swz(lq, lr) << 3;
#pragma unroll 2
  for (int t = 0; t < 16; ++t) {
    __syncthreads();
    int bs = t & 1;
    if (t < 15) stage((t + 1) * 32, bs ^ 1);
    half8 af[4], bf[4];
#pragma unroll
    for (int i = 0; i < 4; ++i)
      af[i] = *(const half8*)&lA[bs][(wr * 64 + i * 16 + lr) * 32 + c16];
#pragma unroll
    for (int j = 0; j < 4; ++j)
      bf[j] = *(const half8*)&lB[bs][(wc * 64 + j * 16 + lr) * 32 + c16];
    __builtin_amdgcn_s_setprio(1);
#pragma unroll
    for (int i = 0; i < 4; ++i)
#pragma unroll
      for (int j = 0; j < 4; ++j)
        acc[i][j] = __builtin_amdgcn_mfma_f32_16x16x32_f16(af[i], bf[j], acc[i][j], 0, 0, 0);
    __builtin_amdgcn_s_setprio(0);
  }

#pragma unroll
  for (int i = 0; i < 4; ++i) {
    int ch0 = tm * 128 + wr * 64 + i * 16 + lq * 4;
    f32x4 b4 = *(const f32x4*)&pb[ch0];
#pragma unroll
    for (int j = 0; j < 4; ++j) {
      int tok = tn * 128 + wc * 64 + j * 16 + lr;
      f32x4 o;
#pragma unroll
      for (int r = 0; r < 4; ++r) o[r] = acc[i][j][r] + b4[r];
      *(f32x4*)&outp[(size_t)tok * 512 + ch0] = o;
    }
  }
}

// ---------------- MFMA attention: 1 wave per (window,head) — UNCHANGED -----
__global__ __launch_bounds__(128) void k_attn(
    const ushort_t* __restrict__ qph, const ushort_t* __restrict__ qpl,
    const ushort_t* __restrict__ kph, const ushort_t* __restrict__ kpl,
    const ushort_t* __restrict__ vt,
    const float* __restrict__ rpb, const float* __restrict__ lsc,
    ushort_t* __restrict__ oh) {
  __shared__ unsigned pw[2][2][64 * 36];   // [wave][P hi/lo][q row * 36 words]
  const int tid = threadIdx.x;
  const int wid = tid >> 6, lane = tid & 63;
  const int pair = blockIdx.x * 2 + wid;   // window*16 + head
  const int h = pair & 15;
  const int l15 = lane & 15, lq = lane >> 4;
  const size_t base = (size_t)pair * 2048;

  half8 Kh[4], Kl[4], Qh[4], Ql[4];
#pragma unroll
  for (int t4 = 0; t4 < 4; ++t4) {
    int off = (t4 * 16 + l15) * 32 + lq * 8;
    Kh[t4] = *(const half8*)(kph + base + off);
    Kl[t4] = *(const half8*)(kpl + base + off);
    Qh[t4] = *(const half8*)(qph + base + off);
    Ql[t4] = *(const half8*)(qpl + base + off);
  }
  f32x4 st[4][4];                          // [kvt][qt]
#pragma unroll
  for (int a = 0; a < 4; ++a)
#pragma unroll
    for (int b = 0; b < 4; ++b)
#pragma unroll
      for (int r = 0; r < 4; ++r) st[a][b][r] = 0.f;
#pragma unroll
  for (int kvt = 0; kvt < 4; ++kvt)
#pragma unroll
    for (int qt = 0; qt < 4; ++qt) {
      st[kvt][qt] = __builtin_amdgcn_mfma_f32_16x16x32_f16(Kh[kvt], Qh[qt], st[kvt][qt], 0, 0, 0);
      st[kvt][qt] = __builtin_amdgcn_mfma_f32_16x16x32_f16(Kh[kvt], Ql[qt], st[kvt][qt], 0, 0, 0);
      st[kvt][qt] = __builtin_amdgcn_mfma_f32_16x16x32_f16(Kl[kvt], Qh[qt], st[kvt][qt], 0, 0, 0);
    }

  const float ls = lsc[h];
  const float* rb = rpb + ((size_t)h << 12);
  float mx[4], sm[4], inv[4];
#pragma unroll
  for (int qt = 0; qt < 4; ++qt) {
    int qg = qt * 16 + l15;
    mx[qt] = -1e30f;
#pragma unroll
    for (int kvt = 0; kvt < 4; ++kvt) {
      f32x4 r4 = *(const f32x4*)(rb + qg * 64 + kvt * 16 + lq * 4);
#pragma unroll
      for (int r = 0; r < 4; ++r) {
        float z = st[kvt][qt][r] * ls + r4[r];
        st[kvt][qt][r] = z;
        mx[qt] = fmaxf(mx[qt], z);
      }
    }
    mx[qt] = fmaxf(mx[qt], __shfl_xor(mx[qt], 16));
    mx[qt] = fmaxf(mx[qt], __shfl_xor(mx[qt], 32));
    sm[qt] = 0.f;
#pragma unroll
    for (int kvt = 0; kvt < 4; ++kvt)
#pragma unroll
      for (int r = 0; r < 4; ++r) {
        float e = __expf(st[kvt][qt][r] - mx[qt]);
        st[kvt][qt][r] = e;
        sm[qt] += e;
      }
    sm[qt] += __shfl_xor(sm[qt], 16);
    sm[qt] += __shfl_xor(sm[qt], 32);
    inv[qt] = 1.f / sm[qt];
  }

#pragma unroll
  for (int qt = 0; qt < 4; ++qt) {
    int qg = qt * 16 + l15;
#pragma unroll
    for (int kvt = 0; kvt < 4; ++kvt)
#pragma unroll
      for (int p2 = 0; p2 < 2; ++p2) {
        float pa = st[kvt][qt][2 * p2] * inv[qt];
        float pc = st[kvt][qt][2 * p2 + 1] * inv[qt];
        half_t ha = (half_t)pa, hc = (half_t)pc;
        unsigned wh = h_bits(ha) | ((unsigned)h_bits(hc) << 16);
        unsigned wl = h_bits((half_t)(pa - (float)ha)) |
                      ((unsigned)h_bits((half_t)(pc - (float)hc)) << 16);
        int kv = kvt * 16 + lq * 4 + 2 * p2;
        pw[wid][0][qg * 36 + (kv >> 1)] = wh;
        pw[wid][1][qg * 36 + (kv >> 1)] = wl;
      }
  }

  half8 Vf[2][2];                          // [dt][ks]
#pragma unroll
  for (int dt = 0; dt < 2; ++dt)
#pragma unroll
    for (int ks = 0; ks < 2; ++ks)
      Vf[dt][ks] = *(const half8*)(vt + base + (dt * 16 + l15) * 64 + ks * 32 + lq * 8);
  f32x4 ot[2][4];                          // [dt][qt]
#pragma unroll
  for (int a = 0; a < 2; ++a)
#pragma unroll
    for (int b = 0; b < 4; ++b)
#pragma unroll
      for (int r = 0; r < 4; ++r) ot[a][b][r] = 0.f;
  const char* pb0 = (const char*)&pw[wid][0][0];
  const char* pb1 = (const char*)&pw[wid][1][0];
#pragma unroll
  for (int qt = 0; qt < 4; ++qt)
#pragma unroll
    for (int ks = 0; ks < 2; ++ks) {
      int off = (qt * 16 + l15) * 144 + ks * 64 + lq * 16;
      half8 Pf = *(const half8*)(pb0 + off);
      half8 Pl = *(const half8*)(pb1 + off);
#pragma unroll
      for (int dt = 0; dt < 2; ++dt) {
        ot[dt][qt] = __builtin_amdgcn_mfma_f32_16x16x32_f16(Vf[dt][ks], Pf, ot[dt][qt], 0, 0, 0);
        ot[dt][qt] = __builtin_amdgcn_mfma_f32_16x16x32_f16(Vf[dt][ks], Pl, ot[dt][qt], 0, 0, 0);
      }
    }

  int win = pair >> 4;
#pragma unroll
  for (int dt = 0; dt < 2; ++dt)
#pragma unroll
    for (int qt = 0; qt < 4; ++qt) {
      int t = win * 64 + qt * 16 + l15;
      int d0 = dt * 16 + lq * 4;
      ushort_t hb[4];
#pragma unroll
      for (int r = 0; r < 4; ++r) hb[r] = h_bits((half_t)ot[dt][qt][r]);
      *(uint2*)&oh[(size_t)t * 512 + h * 32 + d0] =
          make_uint2(hb[0] | ((unsigned)hb[1] << 16), hb[2] | ((unsigned)hb[3] << 16));
    }
}

// ---------------------------------------------------------------------------
extern "C" void kernel_launch(void* const* d_in, const int* in_sizes, int n_in,
                              void* d_out, int out_size, void* d_ws, size_t ws_size,
                              hipStream_t stream) {
  const float* x      = (const float*)d_in[0];
  const float* qkvw   = (const float*)d_in[1];
  const float* qb     = (const float*)d_in[2];
  const float* vb     = (const float*)d_in[3];
  const float* lsc    = (const float*)d_in[4];
  const float* w1     = (const float*)d_in[5];
  const float* b1     = (const float*)d_in[6];
  const float* w2     = (const float*)d_in[7];
  const float* pwt    = (const float*)d_in[8];
  const float* pb     = (const float*)d_in[9];
  const float* coords = (const float*)d_in[10];
  const int*   ridx   = (const int*)d_in[11];
  float* out = (float*)d_out;
  char* ws = (char*)d_ws;

  size_t off = 0;
  auto alloc = [&](size_t bytes) {
    size_t r = off;
    off = (off + bytes + 255) & ~(size_t)255;
    return r;
  };
  size_t oWQH = alloc((size_t)1536 * 512 * 2);
  size_t oWQL = alloc((size_t)1536 * 512 * 2);
  size_t oWPH = alloc((size_t)512 * 512 * 2);
  size_t oRPB = alloc((size_t)16 * 4096 * 4);
  size_t oTBL = alloc((size_t)225 * 16 * 4);
  size_t fixed = off;

  // per-slice planes: qh,ql,kh,kl,vt,ao = 6 * Ms*1024 bytes
  int S = 1;
  while (S <= 32) {
    size_t Ms = (size_t)MROWS / S;
    size_t need = fixed + Ms * 1024 * 6 + 4096;
    if (need <= ws_size) break;
    S <<= 1;
  }
  if (S > 64) S = 64;
  size_t Ms = (size_t)MROWS / S;

  size_t oQH = alloc(Ms * 1024);
  size_t oQL = alloc(Ms * 1024);
  size_t oKH = alloc(Ms * 1024);
  size_t oKL = alloc(Ms * 1024);
  size_t oVT = alloc(Ms * 1024);
  size_t oAO = alloc(Ms * 1024);

  ushort_t* wqh = (ushort_t*)(ws + oWQH);
  ushort_t* wql = (ushort_t*)(ws + oWQL);
  ushort_t* wph = (ushort_t*)(ws + oWPH);
  float* rpb = (float*)(ws + oRPB);
  float* tbl = (float*)(ws + oTBL);
  ushort_t* qh = (ushort_t*)(ws + oQH);
  ushort_t* ql = (ushort_t*)(ws + oQL);
  ushort_t* kh = (ushort_t*)(ws + oKH);
  ushort_t* kl = (ushort_t*)(ws + oKL);
  ushort_t* vt = (ushort_t*)(ws + oVT);
  ushort_t* ao = (ushort_t*)(ws + oAO);

  k_split<<<768, 256, 0, stream>>>(qkvw, wqh, wql, 1536 * 512 / 4);
  k_split_h<<<256, 256, 0, stream>>>(pwt, wph, 512 * 512 / 4);
  k_cpb1<<<225, 256, 0, stream>>>(coords, w1, b1, w2, tbl);
  k_cpb2<<<256, 256, 0, stream>>>(tbl, ridx, rpb);

  int ntn = (int)(Ms / 128);
  int g0 = 12 * ntn;
  int g1 = 4 * ntn;
  int ga = (int)((Ms / 64) * 16 / 2);

  for (int s = 0; s < S; ++s) {
    const float* xs = x + (size_t)s * Ms * 512;
    k_qkv<<<g0, 256, 0, stream>>>(wqh, wql, xs, qb, vb, qh, ql, kh, kl, vt);
    k_attn<<<ga, 128, 0, stream>>>(qh, ql, kh, kl, vt, rpb, lsc, ao);
    k_proj<<<g1, 256, 0, stream>>>(wph, ao, pb, out + (size_t)s * Ms * 512);
  }
  (void)in_sizes; (void)n_in; (void)out_size; (void)ws_size;
}

// Round 10
// 681.364 us; speedup vs baseline: 1.4558x; 1.0687x over previous
//
#include <hip/hip_runtime.h>
#include <hip/hip_bf16.h>
#include <stdint.h>
#include <stddef.h>

// ---------------------------------------------------------------------------
// Swin-V2 window attention, MI355X.  fp16-hi/lo pipeline.
// R10: k_qkv restaged.
//  - x split to fp16-hi ONCE (k_split_h) -> B staged by global_load_lds DMA
//    (no in-loop cvt, no ds_write, no duplicate phase-2 global reads).
//  - A hi+lo co-resident (3 LDS planes, 48KB, 3 blocks/CU): 16 iters,
//    32 MFMA per barrier-pair (Ah*B + Al*B per K-step).
//  - k_proj / k_attn unchanged from R9 (attn numerics frozen).
// ---------------------------------------------------------------------------

typedef unsigned short ushort_t;
typedef _Float16 half_t;
typedef __attribute__((ext_vector_type(8))) _Float16 half8;   // 4 VGPR
typedef __attribute__((ext_vector_type(4))) float f32x4;

#define MROWS 65536   // 1024 windows * 64 tokens

__device__ __forceinline__ ushort_t h_bits(half_t h) {
  union { half_t h; ushort_t u; } c; c.h = h; return c.u;
}

__device__ __forceinline__ void gload16(const void* g, void* l) {
  __builtin_amdgcn_global_load_lds(
      (const __attribute__((address_space(1))) unsigned int*)g,
      (__attribute__((address_space(3))) unsigned int*)l, 16, 0, 0);
}

// ---------------- split fp32 -> fp16 hi + fp16 lo (qkv weights) ------------
__global__ __launch_bounds__(256) void k_split(const float* __restrict__ src,
                                               ushort_t* __restrict__ hi,
                                               ushort_t* __restrict__ lo, int n4) {
  int stride = gridDim.x * blockDim.x;
  for (int i = blockIdx.x * blockDim.x + threadIdx.x; i < n4; i += stride) {
    f32x4 x = reinterpret_cast<const f32x4*>(src)[i];
    ushort_t h4[4], l4[4];
#pragma unroll
    for (int j = 0; j < 4; ++j) {
      half_t hh = (half_t)x[j];
      h4[j] = h_bits(hh);
      l4[j] = h_bits((half_t)(x[j] - (float)hh));
    }
    reinterpret_cast<uint2*>(hi)[i] =
        make_uint2(h4[0] | ((unsigned)h4[1] << 16), h4[2] | ((unsigned)h4[3] << 16));
    reinterpret_cast<uint2*>(lo)[i] =
        make_uint2(l4[0] | ((unsigned)l4[1] << 16), l4[2] | ((unsigned)l4[3] << 16));
  }
}

// hi-only split (proj weight, x slices)
__global__ __launch_bounds__(256) void k_split_h(const float* __restrict__ src,
                                                 ushort_t* __restrict__ hi, int n4) {
  int stride = gridDim.x * blockDim.x;
  for (int i = blockIdx.x * blockDim.x + threadIdx.x; i < n4; i += stride) {
    f32x4 x = reinterpret_cast<const f32x4*>(src)[i];
    ushort_t h4[4];
#pragma unroll
    for (int j = 0; j < 4; ++j) h4[j] = h_bits((half_t)x[j]);
    reinterpret_cast<uint2*>(hi)[i] =
        make_uint2(h4[0] | ((unsigned)h4[1] << 16), h4[2] | ((unsigned)h4[3] << 16));
  }
}

// ---------------- CPB MLP: 225 positions -> 16*sigmoid table ---------------
__global__ __launch_bounds__(256) void k_cpb1(const float* __restrict__ coords,
                                              const float* __restrict__ w1,
                                              const float* __restrict__ b1,
                                              const float* __restrict__ w2,
                                              float* __restrict__ tbl) {
  __shared__ float hid[512];
  int p = blockIdx.x;
  float c0 = coords[2 * p], c1 = coords[2 * p + 1];
  int t = threadIdx.x;
  for (int j = t; j < 512; j += 256) {
    float v = c0 * w1[2 * j] + c1 * w1[2 * j + 1] + b1[j];
    hid[j] = v > 0.f ? v : 0.f;
  }
  __syncthreads();
  int wid = t >> 6, lane = t & 63;
#pragma unroll
  for (int hh = 0; hh < 4; ++hh) {
    int head = wid * 4 + hh;
    float s = 0.f;
    for (int j = lane; j < 512; j += 64) s += hid[j] * w2[head * 512 + j];
#pragma unroll
    for (int off = 32; off > 0; off >>= 1) s += __shfl_xor(s, off);
    if (lane == 0) tbl[p * 16 + head] = 16.f / (1.f + __expf(-s));
  }
}

__global__ __launch_bounds__(256) void k_cpb2(const float* __restrict__ tbl,
                                              const int* __restrict__ ridx,
                                              float* __restrict__ rpb) {
  int idx = blockIdx.x * 256 + threadIdx.x;   // 65536 = 16 heads * 4096
  int h = idx >> 12, nm = idx & 4095;
  rpb[idx] = tbl[ridx[nm] * 16 + h];
}

// 2-bit row-XOR chunk swizzle
__device__ __forceinline__ int swz(int c, int r) {
  return c ^ (r & 3) ^ ((r >> 2) & 3);
}

// ---------------- QKV GEMM: C[ch,tok] = W[ch,K] * Xh[tok,K]^T --------------
// A = W hi+lo co-resident; B = xh fp16, all via global_load_lds DMA.
// 16 iters, 32 MFMA / barrier-pair, LDS 48KB (3 blocks/CU).
__global__ __launch_bounds__(256, 3) void k_qkv(
    const ushort_t* __restrict__ Wh, const ushort_t* __restrict__ Wl,
    const ushort_t* __restrict__ Xh,
    const float* __restrict__ qb, const float* __restrict__ vb,
    ushort_t* __restrict__ oqh, ushort_t* __restrict__ oql,
    ushort_t* __restrict__ okh, ushort_t* __restrict__ okl,
    ushort_t* __restrict__ ovt) {
  __shared__ ushort_t lAh[2][4096];
  __shared__ ushort_t lAl[2][4096];
  __shared__ ushort_t lB[2][4096];

  int nwg = gridDim.x, bid = blockIdx.x;
  int idx = ((nwg & 7) == 0) ? ((bid & 7) * (nwg >> 3) + (bid >> 3)) : bid;
  int tm = idx % 12, tn = idx / 12;    // 12 consecutive idx share tn (xh L2 reuse)
  int tid = threadIdx.x;
  int wid = tid >> 6, lane = tid & 63;
  int wr = wid >> 1, wc = wid & 1;
  int lr = lane & 15, lq = lane >> 4;

  // staging: source chunk pre-swizzled; linear LDS dest (rows r, r+64)
  int rA = tid >> 2, qA = tid & 3;
  int sw = swz(qA, rA) << 3;
  size_t gA = (size_t)(tm * 128 + rA) * 512 + sw;
  size_t gB = (size_t)(tn * 128 + rA) * 512 + sw;
  int dA = wid * 512;

  f32x4 acc[4][4];
#pragma unroll
  for (int i = 0; i < 4; ++i)
#pragma unroll
    for (int j = 0; j < 4; ++j)
#pragma unroll
      for (int r = 0; r < 4; ++r) acc[i][j][r] = 0.f;

  auto stage = [&](int kk, int bs) {
    gload16(Wh + gA + kk, &lAh[bs][dA]);
    gload16(Wh + gA + 32768 + kk, &lAh[bs][2048 + dA]);
    gload16(Wl + gA + kk, &lAl[bs][dA]);
    gload16(Wl + gA + 32768 + kk, &lAl[bs][2048 + dA]);
    gload16(Xh + gB + kk, &lB[bs][dA]);
    gload16(Xh + gB + 32768 + kk, &lB[bs][2048 + dA]);
  };

  stage(0, 0);
  const int c16 = swz(lq, lr) << 3;   // read-side inverse swizzle
#pragma unroll 2
  for (int t = 0; t < 16; ++t) {
    __syncthreads();
    int bs = t & 1;
    if (t < 15) stage((t + 1) * 32, bs ^ 1);
    half8 ah[4], al[4], bf[4];
#pragma unroll
    for (int i = 0; i < 4; ++i) {
      int ro = (wr * 64 + i * 16 + lr) * 32 + c16;
      ah[i] = *(const half8*)&lAh[bs][ro];
      al[i] = *(const half8*)&lAl[bs][ro];
    }
#pragma unroll
    for (int j = 0; j < 4; ++j)
      bf[j] = *(const half8*)&lB[bs][(wc * 64 + j * 16 + lr) * 32 + c16];
    __builtin_amdgcn_s_setprio(1);
#pragma unroll
    for (int i = 0; i < 4; ++i)
#pragma unroll
      for (int j = 0; j < 4; ++j) {
        acc[i][j] = __builtin_amdgcn_mfma_f32_16x16x32_f16(ah[i], bf[j], acc[i][j], 0, 0, 0);
        acc[i][j] = __builtin_amdgcn_mfma_f32_16x16x32_f16(al[i], bf[j], acc[i][j], 0, 0, 0);
      }
    __builtin_amdgcn_s_setprio(0);
  }

  // C layout: col = lane&15 (token), row = (lane>>4)*4 + reg (channel)
#pragma unroll
  for (int i = 0; i < 4; ++i) {
    int ch0 = tm * 128 + wr * 64 + i * 16 + lq * 4;
#pragma unroll
    for (int j = 0; j < 4; ++j) {
      int tok = tn * 128 + wc * 64 + j * 16 + lr;
      int sec = tm >> 2;                 // block-uniform: 0=q,1=k,2=v
      int h = (ch0 >> 5) & 15, d0 = ch0 & 31;
      int win = tok >> 6, n = tok & 63;
      size_t pr = (size_t)win * 16 + h;
      f32x4 b4;
      if (sec == 0)      b4 = *(const f32x4*)&qb[ch0];
      else if (sec == 2) b4 = *(const f32x4*)&vb[ch0 - 1024];
      else { b4[0] = 0.f; b4[1] = 0.f; b4[2] = 0.f; b4[3] = 0.f; }
      if (sec == 2) {
#pragma unroll
        for (int r = 0; r < 4; ++r) {
          float v = acc[i][j][r] + b4[r];
          ovt[(pr * 32 + d0 + r) * 64 + n] = h_bits((half_t)v);
        }
      } else {
        ushort_t hb[4], lb4[4];
#pragma unroll
        for (int r = 0; r < 4; ++r) {
          float v = acc[i][j][r] + b4[r];
          half_t hh = (half_t)v;
          hb[r] = h_bits(hh);
          lb4[r] = h_bits((half_t)(v - (float)hh));
        }
        uint2 hw = make_uint2(hb[0] | ((unsigned)hb[1] << 16), hb[2] | ((unsigned)hb[3] << 16));
        uint2 lw = make_uint2(lb4[0] | ((unsigned)lb4[1] << 16), lb4[2] | ((unsigned)lb4[3] << 16));
        size_t o = (pr * 64 + n) * 32 + d0;
        if (sec == 0) { *(uint2*)&oqh[o] = hw; *(uint2*)&oql[o] = lw; }
        else          { *(uint2*)&okh[o] = hw; *(uint2*)&okl[o] = lw; }
      }
    }
  }
}

// ---------------- proj GEMM: plain fp16, C = Wp * AO^T ---------------------
__global__ __launch_bounds__(256, 4) void k_proj(
    const ushort_t* __restrict__ Wh,
    const ushort_t* __restrict__ Bp,
    const float* __restrict__ pb, float* __restrict__ outp) {
  __shared__ ushort_t lA[2][4096];
  __shared__ ushort_t lB[2][4096];

  int nwg = gridDim.x, bid = blockIdx.x;
  int idx = ((nwg & 7) == 0) ? ((bid & 7) * (nwg >> 3) + (bid >> 3)) : bid;
  int tm = idx % 4, tn = idx / 4;
  int tid = threadIdx.x;
  int wid = tid >> 6, lane = tid & 63;
  int wr = wid >> 1, wc = wid & 1;
  int lr = lane & 15, lq = lane >> 4;

  int rA = tid >> 2, qA = tid & 3;
  int sw = swz(qA, rA) << 3;
  size_t gA = (size_t)(tm * 128 + rA) * 512 + sw;
  size_t gB = (size_t)(tn * 128 + rA) * 512 + sw;
  int dA = wid * 512;

  f32x4 acc[4][4];
#pragma unroll
  for (int i = 0; i < 4; ++i)
#pragma unroll
    for (int j = 0; j < 4; ++j)
#pragma unroll
      for (int r = 0; r < 4; ++r) acc[i][j][r] = 0.f;

  auto stage = [&](int kk, int bs) {
    gload16(Wh + gA + kk, &lA[bs][dA]);
    gload16(Wh + gA + 32768 + kk, &lA[bs][2048 + dA]);
    gload16(Bp + gB + kk, &lB[bs][dA]);
    gload16(Bp + gB + 32768 + kk, &lB[bs][2048 + dA]);
  };

  stage(0, 0);
  const int c16 = swz(lq, lr) << 3;
#pragma unroll 2
  for (int t = 0; t < 16; ++t) {
    __syncthreads();
    int bs = t & 1;
    if (t < 15) stage((t + 1) * 32, bs ^ 1);
    half8 af[4], bf[4];
#pragma unroll
    for (int i = 0; i < 4; ++i)
      af[i] = *(const half8*)&lA[bs][(wr * 64 + i * 16 + lr) * 32 + c16];
#pragma unroll
    for (int j = 0; j < 4; ++j)
      bf[j] = *(const half8*)&lB[bs][(wc * 64 + j * 16 + lr) * 32 + c16];
    __builtin_amdgcn_s_setprio(1);
#pragma unroll
    for (int i = 0; i < 4; ++i)
#pragma unroll
      for (int j = 0; j < 4; ++j)
        acc[i][j] = __builtin_amdgcn_mfma_f32_16x16x32_f16(af[i], bf[j], acc[i][j], 0, 0, 0);
    __builtin_amdgcn_s_setprio(0);
  }

#pragma unroll
  for (int i = 0; i < 4; ++i) {
    int ch0 = tm * 128 + wr * 64 + i * 16 + lq * 4;
    f32x4 b4 = *(const f32x4*)&pb[ch0];
#pragma unroll
    for (int j = 0; j < 4; ++j) {
      int tok = tn * 128 + wc * 64 + j * 16 + lr;
      f32x4 o;
#pragma unroll
      for (int r = 0; r < 4; ++r) o[r] = acc[i][j][r] + b4[r];
      *(f32x4*)&outp[(size_t)tok * 512 + ch0] = o;
    }
  }
}

// ---------------- MFMA attention: 1 wave per (window,head) — UNCHANGED -----
__global__ __launch_bounds__(128) void k_attn(
    const ushort_t* __restrict__ qph, const ushort_t* __restrict__ qpl,
    const ushort_t* __restrict__ kph, const ushort_t* __restrict__ kpl,
    const ushort_t* __restrict__ vt,
    const float* __restrict__ rpb, const float* __restrict__ lsc,
    ushort_t* __restrict__ oh) {
  __shared__ unsigned pw[2][2][64 * 36];   // [wave][P hi/lo][q row * 36 words]
  const int tid = threadIdx.x;
  const int wid = tid >> 6, lane = tid & 63;
  const int pair = blockIdx.x * 2 + wid;   // window*16 + head
  const int h = pair & 15;
  const int l15 = lane & 15, lq = lane >> 4;
  const size_t base = (size_t)pair * 2048;

  half8 Kh[4], Kl[4], Qh[4], Ql[4];
#pragma unroll
  for (int t4 = 0; t4 < 4; ++t4) {
    int off = (t4 * 16 + l15) * 32 + lq * 8;
    Kh[t4] = *(const half8*)(kph + base + off);
    Kl[t4] = *(const half8*)(kpl + base + off);
    Qh[t4] = *(const half8*)(qph + base + off);
    Ql[t4] = *(const half8*)(qpl + base + off);
  }
  f32x4 st[4][4];                          // [kvt][qt]
#pragma unroll
  for (int a = 0; a < 4; ++a)
#pragma unroll
    for (int b = 0; b < 4; ++b)
#pragma unroll
      for (int r = 0; r < 4; ++r) st[a][b][r] = 0.f;
#pragma unroll
  for (int kvt = 0; kvt < 4; ++kvt)
#pragma unroll
    for (int qt = 0; qt < 4; ++qt) {
      st[kvt][qt] = __builtin_amdgcn_mfma_f32_16x16x32_f16(Kh[kvt], Qh[qt], st[kvt][qt], 0, 0, 0);
      st[kvt][qt] = __builtin_amdgcn_mfma_f32_16x16x32_f16(Kh[kvt], Ql[qt], st[kvt][qt], 0, 0, 0);
      st[kvt][qt] = __builtin_amdgcn_mfma_f32_16x16x32_f16(Kl[kvt], Qh[qt], st[kvt][qt], 0, 0, 0);
    }

  const float ls = lsc[h];
  const float* rb = rpb + ((size_t)h << 12);
  float mx[4], sm[4], inv[4];
#pragma unroll
  for (int qt = 0; qt < 4; ++qt) {
    int qg = qt * 16 + l15;
    mx[qt] = -1e30f;
#pragma unroll
    for (int kvt = 0; kvt < 4; ++kvt) {
      f32x4 r4 = *(const f32x4*)(rb + qg * 64 + kvt * 16 + lq * 4);
#pragma unroll
      for (int r = 0; r < 4; ++r) {
        float z = st[kvt][qt][r] * ls + r4[r];
        st[kvt][qt][r] = z;
        mx[qt] = fmaxf(mx[qt], z);
      }
    }
    mx[qt] = fmaxf(mx[qt], __shfl_xor(mx[qt], 16));
    mx[qt] = fmaxf(mx[qt], __shfl_xor(mx[qt], 32));
    sm[qt] = 0.f;
#pragma unroll
    for (int kvt = 0; kvt < 4; ++kvt)
#pragma unroll
      for (int r = 0; r < 4; ++r) {
        float e = __expf(st[kvt][qt][r] - mx[qt]);
        st[kvt][qt][r] = e;
        sm[qt] += e;
      }
    sm[qt] += __shfl_xor(sm[qt], 16);
    sm[qt] += __shfl_xor(sm[qt], 32);
    inv[qt] = 1.f / sm[qt];
  }

#pragma unroll
  for (int qt = 0; qt < 4; ++qt) {
    int qg = qt * 16 + l15;
#pragma unroll
    for (int kvt = 0; kvt < 4; ++kvt)
#pragma unroll
      for (int p2 = 0; p2 < 2; ++p2) {
        float pa = st[kvt][qt][2 * p2] * inv[qt];
        float pc = st[kvt][qt][2 * p2 + 1] * inv[qt];
        half_t ha = (half_t)pa, hc = (half_t)pc;
        unsigned wh = h_bits(ha) | ((unsigned)h_bits(hc) << 16);
        unsigned wl = h_bits((half_t)(pa - (float)ha)) |
                      ((unsigned)h_bits((half_t)(pc - (float)hc)) << 16);
        int kv = kvt * 16 + lq * 4 + 2 * p2;
        pw[wid][0][qg * 36 + (kv >> 1)] = wh;
        pw[wid][1][qg * 36 + (kv >> 1)] = wl;
      }
  }

  half8 Vf[2][2];                          // [dt][ks]
#pragma unroll
  for (int dt = 0; dt < 2; ++dt)
#pragma unroll
    for (int ks = 0; ks < 2; ++ks)
      Vf[dt][ks] = *(const half8*)(vt + base + (dt * 16 + l15) * 64 + ks * 32 + lq * 8);
  f32x4 ot[2][4];                          // [dt][qt]
#pragma unroll
  for (int a = 0; a < 2; ++a)
#pragma unroll
    for (int b = 0; b < 4; ++b)
#pragma unroll
      for (int r = 0; r < 4; ++r) ot[a][b][r] = 0.f;
  const char* pb0 = (const char*)&pw[wid][0][0];
  const char* pb1 = (const char*)&pw[wid][1][0];
#pragma unroll
  for (int qt = 0; qt < 4; ++qt)
#pragma unroll
    for (int ks = 0; ks < 2; ++ks) {
      int off = (qt * 16 + l15) * 144 + ks * 64 + lq * 16;
      half8 Pf = *(const half8*)(pb0 + off);
      half8 Pl = *(const half8*)(pb1 + off);
#pragma unroll
      for (int dt = 0; dt < 2; ++dt) {
        ot[dt][qt] = __builtin_amdgcn_mfma_f32_16x16x32_f16(Vf[dt][ks], Pf, ot[dt][qt], 0, 0, 0);
        ot[dt][qt] = __builtin_amdgcn_mfma_f32_16x16x32_f16(Vf[dt][ks], Pl, ot[dt][qt], 0, 0, 0);
      }
    }

  int win = pair >> 4;
#pragma unroll
  for (int dt = 0; dt < 2; ++dt)
#pragma unroll
    for (int qt = 0; qt < 4; ++qt) {
      int t = win * 64 + qt * 16 + l15;
      int d0 = dt * 16 + lq * 4;
      ushort_t hb[4];
#pragma unroll
      for (int r = 0; r < 4; ++r) hb[r] = h_bits((half_t)ot[dt][qt][r]);
      *(uint2*)&oh[(size_t)t * 512 + h * 32 + d0] =
          make_uint2(hb[0] | ((unsigned)hb[1] << 16), hb[2] | ((unsigned)hb[3] << 16));
    }
}

// ---------------------------------------------------------------------------
extern "C" void kernel_launch(void* const* d_in, const int* in_sizes, int n_in,
                              void* d_out, int out_size, void* d_ws, size_t ws_size,
                              hipStream_t stream) {
  const float* x      = (const float*)d_in[0];
  const float* qkvw   = (const float*)d_in[1];
  const float* qb     = (const float*)d_in[2];
  const float* vb     = (const float*)d_in[3];
  const float* lsc    = (const float*)d_in[4];
  const float* w1     = (const float*)d_in[5];
  const float* b1     = (const float*)d_in[6];
  const float* w2     = (const float*)d_in[7];
  const float* pwt    = (const float*)d_in[8];
  const float* pb     = (const float*)d_in[9];
  const float* coords = (const float*)d_in[10];
  const int*   ridx   = (const int*)d_in[11];
  float* out = (float*)d_out;
  char* ws = (char*)d_ws;

  size_t off = 0;
  auto alloc = [&](size_t bytes) {
    size_t r = off;
    off = (off + bytes + 255) & ~(size_t)255;
    return r;
  };
  size_t oWQH = alloc((size_t)1536 * 512 * 2);
  size_t oWQL = alloc((size_t)1536 * 512 * 2);
  size_t oWPH = alloc((size_t)512 * 512 * 2);
  size_t oRPB = alloc((size_t)16 * 4096 * 4);
  size_t oTBL = alloc((size_t)225 * 16 * 4);
  size_t fixed = off;

  // per-slice planes: xh,qh,ql,kh,kl,vt,ao = 7 * Ms*1024 bytes
  int S = 1;
  while (S <= 32) {
    size_t Ms = (size_t)MROWS / S;
    size_t need = fixed + Ms * 1024 * 7 + 4096;
    if (need <= ws_size) break;
    S <<= 1;
  }
  if (S > 64) S = 64;
  size_t Ms = (size_t)MROWS / S;

  size_t oXH = alloc(Ms * 1024);
  size_t oQH = alloc(Ms * 1024);
  size_t oQL = alloc(Ms * 1024);
  size_t oKH = alloc(Ms * 1024);
  size_t oKL = alloc(Ms * 1024);
  size_t oVT = alloc(Ms * 1024);
  size_t oAO = alloc(Ms * 1024);

  ushort_t* wqh = (ushort_t*)(ws + oWQH);
  ushort_t* wql = (ushort_t*)(ws + oWQL);
  ushort_t* wph = (ushort_t*)(ws + oWPH);
  float* rpb = (float*)(ws + oRPB);
  float* tbl = (float*)(ws + oTBL);
  ushort_t* xh = (ushort_t*)(ws + oXH);
  ushort_t* qh = (ushort_t*)(ws + oQH);
  ushort_t* ql = (ushort_t*)(ws + oQL);
  ushort_t* kh = (ushort_t*)(ws + oKH);
  ushort_t* kl = (ushort_t*)(ws + oKL);
  ushort_t* vt = (ushort_t*)(ws + oVT);
  ushort_t* ao = (ushort_t*)(ws + oAO);

  k_split<<<768, 256, 0, stream>>>(qkvw, wqh, wql, 1536 * 512 / 4);
  k_split_h<<<256, 256, 0, stream>>>(pwt, wph, 512 * 512 / 4);
  k_cpb1<<<225, 256, 0, stream>>>(coords, w1, b1, w2, tbl);
  k_cpb2<<<256, 256, 0, stream>>>(tbl, ridx, rpb);

  int n4x = (int)(Ms * 512 / 4);
  int gsplit = (n4x + 255) / 256;
  if (gsplit > 2048) gsplit = 2048;
  int ntn = (int)(Ms / 128);
  int g0 = 12 * ntn;
  int g1 = 4 * ntn;
  int ga = (int)((Ms / 64) * 16 / 2);

  for (int s = 0; s < S; ++s) {
    const float* xs = x + (size_t)s * Ms * 512;
    k_split_h<<<gsplit, 256, 0, stream>>>(xs, xh, n4x);
    k_qkv<<<g0, 256, 0, stream>>>(wqh, wql, xh, qb, vb, qh, ql, kh, kl, vt);
    k_attn<<<ga, 128, 0, stream>>>(qh, ql, kh, kl, vt, rpb, lsc, ao);
    k_proj<<<g1, 256, 0, stream>>>(wph, ao, pb, out + (size_t)s * Ms * 512);
  }
  (void)in_sizes; (void)n_in; (void)out_size; (void)ws_size;
}